// Round 2
// baseline (1653.531 us; speedup 1.0000x reference)
//
#include <hip/hip_runtime.h>
#include <hip/hip_cooperative_groups.h>
#include <math.h>

namespace cg = cooperative_groups;

// ---------------- problem constants ----------------
#define Lsz   1024
#define Tsz   32
#define Bsz   64
#define DIN   300
#define REG   36
#define Rsz   128
#define R3sz  384
#define H3sz  3072
#define GENROWS 49152   // R3sz * Rsz
#define NC    2048      // caption columns c = t*64 + b
#define KPAD  304       // DIN padded to /16 (fp32 path)

typedef __attribute__((ext_vector_type(8))) short bf16x8;
typedef __attribute__((ext_vector_type(4))) float f32x4;

__device__ __forceinline__ float sigf(float x) { return 1.f / (1.f + __expf(-x)); }

// f32 -> bf16 (RNE) bit trick; and back.
__device__ __forceinline__ ushort f2bf(float x) {
    unsigned u = __float_as_uint(x);
    unsigned r = (u + 0x7fffu + ((u >> 16) & 1u)) >> 16;
    return (ushort)r;
}
__device__ __forceinline__ float bf2f(ushort h) {
    return __uint_as_float((unsigned)h << 16);
}

// Fragment layout for mfma_f32_16x16x32_bf16 operands:
//   A[m][k]: m = lane&15, k-slot = (lane>>4)*8 + elem   (contiguous 8)
//   B[k][n]: n = lane&15, same k-slot structure.
// Both packs use the same slot->k map, so the map cancels in the dot.
// C/D (measured, m89): col = lane&15, row = (lane>>4)*4 + reg.
// Frag storage: frag_idx*512 + lane*8 + elem (ushort units; 1 KB/frag).

// h-fragment byte-slot for B-operand pack: k = h-dim, b = batch col.
__device__ __forceinline__ size_t hfrag_off(int k, int b) {
    return (((size_t)(k >> 5) * 4 + (b >> 4)) * 64 +
            ((((k >> 3) & 3) << 4) | (b & 15))) * 8 + (k & 7);
}

__device__ __forceinline__ void pack8(const float* v, ushort* dsth, ushort* dstl) {
    unsigned hw[4], lw[4];
#pragma unroll
    for (int e2 = 0; e2 < 4; e2++) {
        ushort h0 = f2bf(v[2 * e2]);
        ushort h1 = f2bf(v[2 * e2 + 1]);
        ushort l0 = f2bf(v[2 * e2] - bf2f(h0));
        ushort l1 = f2bf(v[2 * e2 + 1] - bf2f(h1));
        hw[e2] = (unsigned)h0 | ((unsigned)h1 << 16);
        lw[e2] = (unsigned)l0 | ((unsigned)l1 << 16);
    }
    *(uint4*)dsth = make_uint4(hw[0], hw[1], hw[2], hw[3]);
    *(uint4*)dstl = make_uint4(lw[0], lw[1], lw[2], lw[3]);
}

// =====================================================================
// Generic transpose: out[c*R + r] = in[r*lda + woff + c], c < Cin,
// zero-pad c in [Cin, Cpad). grid (ceil(Cpad/64), ceil(R/64)).
// =====================================================================
__global__ __launch_bounds__(256) void transp_kernel(
    const float* __restrict__ in, float* __restrict__ out,
    int R, int Cin, int Cpad, int lda, int woff)
{
    __shared__ float s[64][65];
    int c0 = blockIdx.x * 64, r0 = blockIdx.y * 64;
    int tid = threadIdx.x;
#pragma unroll
    for (int l = 0; l < 16; l++) {
        int e = l * 256 + tid;
        int rr = e >> 6, cc = e & 63;
        int r = r0 + rr, c = c0 + cc;
        s[rr][cc] = (r < R && c < Cin) ? in[(size_t)r * lda + woff + c] : 0.f;
    }
    __syncthreads();
#pragma unroll
    for (int l = 0; l < 16; l++) {
        int e = l * 256 + tid;
        int cc = e >> 6, rr = e & 63;
        int c = c0 + cc, r = r0 + rr;
        if (c < Cpad && r < R) out[(size_t)c * R + r] = s[rr][cc];
    }
}

// =====================================================================
// cap_embed [b][t][d] -> capTr [k][t*64+b], k zero-padded to 304.
// =====================================================================
__global__ __launch_bounds__(256) void captr_kernel(
    const float* __restrict__ cap_embed, float* __restrict__ capTr)
{
    __shared__ float s[64][65];
    int t = blockIdx.x, kc = blockIdx.y;
    int tid = threadIdx.x;
#pragma unroll
    for (int l = 0; l < 16; l++) {
        int e = l * 256 + tid;
        int b = e >> 6, kk = e & 63;
        int k = kc * 64 + kk;
        s[b][kk] = (k < DIN) ? cap_embed[((size_t)b * Tsz + t) * DIN + k] : 0.f;
    }
    __syncthreads();
#pragma unroll
    for (int l = 0; l < 16; l++) {
        int e = l * 256 + tid;
        int kk = e >> 6, b = e & 63;
        int k = kc * 64 + kk;
        if (k < KPAD)
            capTr[(size_t)k * NC + t * 64 + b] = s[b][kk];
    }
}

// =====================================================================
// All-transposed GEMM (fp32): C[n][c] = sum_k WT[k][n]*X[k][c] + bias[n].
// Now only used for the small cap_reduced GEMM.
// =====================================================================
__global__ __launch_bounds__(256) void gemm_tt(
    const float* __restrict__ WT1, const float* __restrict__ WT2,
    const float* __restrict__ X,
    const float* __restrict__ b1, const float* __restrict__ b2,
    float* __restrict__ C1, float* __restrict__ C2, int Ntot)
{
    const float* WT = blockIdx.z ? WT2 : WT1;
    const float* bias = blockIdx.z ? b2 : b1;
    float* C = blockIdx.z ? C2 : C1;
    __shared__ float Ws[16][132];
    __shared__ float Xs[16][132];
    int tid = threadIdx.x, tx = tid & 15, ty = tid >> 4;
    int c0 = blockIdx.x * 128, n0 = blockIdx.y * 128;
    float acc[8][8];
#pragma unroll
    for (int i = 0; i < 8; i++)
#pragma unroll
        for (int j = 0; j < 8; j++) acc[i][j] = 0.f;

    for (int k0 = 0; k0 < KPAD; k0 += 16) {
#pragma unroll
        for (int l = 0; l < 2; l++) {
            int e = l * 256 + tid;
            int l16 = e & 15, seg = e >> 4;
            int kk = seg & 15, half = seg >> 4;
            int col = half * 64 + l16 * 4;
            *(float4*)&Ws[kk][col] = *(const float4*)&WT[(size_t)(k0 + kk) * Ntot + n0 + col];
            *(float4*)&Xs[kk][col] = *(const float4*)&X[(size_t)(k0 + kk) * NC + c0 + col];
        }
        __syncthreads();
#pragma unroll
        for (int kk = 0; kk < 16; kk++) {
            float a[8], x[8];
            *(float4*)&a[0] = *(const float4*)&Ws[kk][ty * 8];
            *(float4*)&a[4] = *(const float4*)&Ws[kk][ty * 8 + 4];
            *(float4*)&x[0] = *(const float4*)&Xs[kk][tx * 4];
            *(float4*)&x[4] = *(const float4*)&Xs[kk][64 + tx * 4];
#pragma unroll
            for (int i = 0; i < 8; i++)
#pragma unroll
                for (int j = 0; j < 8; j++) acc[i][j] = fmaf(a[i], x[j], acc[i][j]);
        }
        __syncthreads();
    }
#pragma unroll
    for (int i = 0; i < 8; i++) {
        int n = n0 + ty * 8 + i;
        float bv = bias[n];
        *(float4*)&C[(size_t)n * NC + c0 + tx * 4] =
            make_float4(acc[i][0] + bv, acc[i][1] + bv, acc[i][2] + bv, acc[i][3] + bv);
        *(float4*)&C[(size_t)n * NC + c0 + 64 + tx * 4] =
            make_float4(acc[i][4] + bv, acc[i][5] + bv, acc[i][6] + bv, acc[i][7] + bv);
    }
}

// =====================================================================
// Parametrized TT GEMM with K-split: z selects k-range.
// =====================================================================
__global__ __launch_bounds__(256) void gemm_ttp(
    const float* __restrict__ WT, const float* __restrict__ X,
    float* __restrict__ C, int Ntot, int ncols, int klen)
{
    int z = blockIdx.z;
    int kbase = z * klen;
    float* Cp = C + (size_t)z * Ntot * ncols;
    __shared__ float Ws[16][132];
    __shared__ float Xs[16][132];
    int tid = threadIdx.x, tx = tid & 15, ty = tid >> 4;
    int c0 = blockIdx.x * 128, n0 = blockIdx.y * 128;
    float acc[8][8];
#pragma unroll
    for (int i = 0; i < 8; i++)
#pragma unroll
        for (int j = 0; j < 8; j++) acc[i][j] = 0.f;

    for (int k0 = 0; k0 < klen; k0 += 16) {
#pragma unroll
        for (int l = 0; l < 2; l++) {
            int e = l * 256 + tid;
            int l16 = e & 15, seg = e >> 4;
            int kk = seg & 15, half = seg >> 4;
            int col = half * 64 + l16 * 4;
            *(float4*)&Ws[kk][col] =
                *(const float4*)&WT[(size_t)(kbase + k0 + kk) * Ntot + n0 + col];
            *(float4*)&Xs[kk][col] =
                *(const float4*)&X[(size_t)(kbase + k0 + kk) * ncols + c0 + col];
        }
        __syncthreads();
#pragma unroll
        for (int kk = 0; kk < 16; kk++) {
            float a[8], x[8];
            *(float4*)&a[0] = *(const float4*)&Ws[kk][ty * 8];
            *(float4*)&a[4] = *(const float4*)&Ws[kk][ty * 8 + 4];
            *(float4*)&x[0] = *(const float4*)&Xs[kk][tx * 4];
            *(float4*)&x[4] = *(const float4*)&Xs[kk][64 + tx * 4];
#pragma unroll
            for (int i = 0; i < 8; i++)
#pragma unroll
                for (int j = 0; j < 8; j++) acc[i][j] = fmaf(a[i], x[j], acc[i][j]);
        }
        __syncthreads();
    }
#pragma unroll
    for (int i = 0; i < 8; i++) {
        int n = n0 + ty * 8 + i;
        *(float4*)&Cp[(size_t)n * ncols + c0 + tx * 4] =
            make_float4(acc[i][0], acc[i][1], acc[i][2], acc[i][3]);
        *(float4*)&Cp[(size_t)n * ncols + c0 + 64 + tx * 4] =
            make_float4(acc[i][4], acc[i][5], acc[i][6], acc[i][7]);
    }
}

// =====================================================================
// q/k projection as K-split TT GEMM. grid (16 cblk, 2 qk, 8 z).
// =====================================================================
__global__ __launch_bounds__(256) void gemm_qk(
    const float* __restrict__ WqT, const float* __restrict__ WkT,
    const float* __restrict__ X,
    float* __restrict__ qP, float* __restrict__ kP)
{
    int qk = blockIdx.y, z = blockIdx.z;
    const float* WT = qk ? WkT : WqT;
    float* Cp = (qk ? kP : qP) + (size_t)z * Rsz * NC;
    int kbase = z * 128;
    __shared__ float Ws[16][132];
    __shared__ float Xs[16][132];
    int tid = threadIdx.x, tx = tid & 15, ty = tid >> 4;
    int c0 = blockIdx.x * 128;
    float acc[8][8];
#pragma unroll
    for (int i = 0; i < 8; i++)
#pragma unroll
        for (int j = 0; j < 8; j++) acc[i][j] = 0.f;

    for (int k0 = 0; k0 < 128; k0 += 16) {
#pragma unroll
        for (int l = 0; l < 2; l++) {
            int e = l * 256 + tid;
            int l16 = e & 15, seg = e >> 4;
            int kk = seg & 15, half = seg >> 4;
            int col = half * 64 + l16 * 4;
            if (half == 0)
                *(float4*)&Ws[kk][col] =
                    *(const float4*)&WT[(size_t)(kbase + k0 + kk) * Rsz + col];
            else
                *(float4*)&Ws[kk][col] =
                    *(const float4*)&WT[(size_t)(kbase + k0 + kk) * Rsz + col - 64 + 64];
            *(float4*)&Xs[kk][col] =
                *(const float4*)&X[(size_t)(kbase + k0 + kk) * NC + c0 + col];
        }
        __syncthreads();
#pragma unroll
        for (int kk = 0; kk < 16; kk++) {
            float a[8], x[8];
            *(float4*)&a[0] = *(const float4*)&Ws[kk][ty * 8];
            *(float4*)&a[4] = *(const float4*)&Ws[kk][ty * 8 + 4];
            *(float4*)&x[0] = *(const float4*)&Xs[kk][tx * 4];
            *(float4*)&x[4] = *(const float4*)&Xs[kk][64 + tx * 4];
#pragma unroll
            for (int i = 0; i < 8; i++)
#pragma unroll
                for (int j = 0; j < 8; j++) acc[i][j] = fmaf(a[i], x[j], acc[i][j]);
        }
        __syncthreads();
    }
#pragma unroll
    for (int i = 0; i < 8; i++) {
        int n = ty * 8 + i;
        *(float4*)&Cp[(size_t)n * NC + c0 + tx * 4] =
            make_float4(acc[i][0], acc[i][1], acc[i][2], acc[i][3]);
        *(float4*)&Cp[(size_t)n * NC + c0 + 64 + tx * 4] =
            make_float4(acc[i][4], acc[i][5], acc[i][6], acc[i][7]);
    }
}

// =====================================================================
// qk combine: sum 8 partials + bias, transpose to [b][t][o] layout.
// =====================================================================
__global__ __launch_bounds__(256) void qkc_kernel(
    const float* __restrict__ qP, const float* __restrict__ kP,
    const float* __restrict__ sa_bq, const float* __restrict__ sa_bk,
    float* __restrict__ qbuf, float* __restrict__ kbuf)
{
    __shared__ float s[128][65];
    int t = blockIdx.x, qk = blockIdx.y;
    const float* P = qk ? kP : qP;
    const float* bias = qk ? sa_bk : sa_bq;
    float* dst = qk ? kbuf : qbuf;
    int tid = threadIdx.x;
    for (int e = tid; e < 128 * 64; e += 256) {
        int o = e >> 6, b = e & 63;
        size_t idx = (size_t)o * NC + t * 64 + b;
        float v = 0.f;
#pragma unroll
        for (int z = 0; z < 8; z++)
            v += P[(size_t)z * Rsz * NC + idx];
        s[o][b] = v;
    }
    __syncthreads();
    for (int e = tid; e < 128 * 64; e += 256) {
        int b = e >> 7, o = e & 127;
        dst[((size_t)b * Tsz + t) * Rsz + o] = s[o][b] + bias[o];
    }
}

// =====================================================================
// Generated weights GEMM -> WihAllT/WhhAllT [i][k][row]. grid (3,129,2).
// =====================================================================
__global__ __launch_bounds__(256) void genw_gemm(
    const float* __restrict__ gen_Wih, const float* __restrict__ gen_bih,
    const float* __restrict__ gen_Whh, const float* __restrict__ gen_bhh,
    const float* __restrict__ gen_Wbih, const float* __restrict__ gen_bbih,
    const float* __restrict__ gen_Wbhh, const float* __restrict__ gen_bbhh,
    const float* __restrict__ base,
    float* __restrict__ WihAllT, float* __restrict__ WhhAllT,
    float* __restrict__ bihAll, float* __restrict__ bhhAll)
{
    __shared__ float Bs[64][132];
    __shared__ float Ws[16][132];
    __shared__ float bs[128];
    int rtile = blockIdx.x, ky = blockIdx.y, mat = blockIdx.z;
    int r0 = rtile * 128;
    bool normal = (ky < 128);
    int k = normal ? ky : 0;
    const float* W  = normal ? (mat ? gen_Whh : gen_Wih) : (mat ? gen_Wbhh : gen_Wbih);
    const float* bi = normal ? (mat ? gen_bhh : gen_bih) : (mat ? gen_bbhh : gen_bbih);
    float* out      = normal ? (mat ? WhhAllT : WihAllT) : (mat ? bhhAll : bihAll);
    int rowmul = normal ? 128 : 1;
    size_t ostride = normal ? (size_t)GENROWS : (size_t)R3sz;
    size_t obase   = normal ? (size_t)k * R3sz + r0 : (size_t)r0;

    int tid = threadIdx.x, tx = tid & 15, ty = tid >> 4;
#pragma unroll
    for (int l = 0; l < 8; l++) {
        int e = l * 256 + tid;
        int i = e >> 5, p4 = (e & 31) * 4;
        *(float4*)&Bs[i][p4] = *(const float4*)&base[(size_t)i * Rsz + p4];
    }
    if (tid < 128) bs[tid] = bi[(size_t)(r0 + tid) * rowmul + k];

    float acc[4][8];
#pragma unroll
    for (int i = 0; i < 4; i++)
#pragma unroll
        for (int j = 0; j < 8; j++) acc[i][j] = 0.f;

    for (int c = 0; c < 8; c++) {
        int p0 = c * 16;
#pragma unroll
        for (int l = 0; l < 2; l++) {
            int e = l * 256 + tid;
            int rr = e >> 2, pq = (e & 3) * 4;
            size_t rowidx = (size_t)(r0 + rr) * rowmul + k;
            float4 v = *(const float4*)&W[rowidx * Rsz + p0 + pq];
            Ws[pq + 0][rr] = v.x;
            Ws[pq + 1][rr] = v.y;
            Ws[pq + 2][rr] = v.z;
            Ws[pq + 3][rr] = v.w;
        }
        __syncthreads();
#pragma unroll
        for (int kk = 0; kk < 16; kk++) {
            float a[4], b8[8];
#pragma unroll
            for (int ii = 0; ii < 4; ii++) a[ii] = Bs[ty * 4 + ii][p0 + kk];
            *(float4*)&b8[0] = *(const float4*)&Ws[kk][tx * 4];
            *(float4*)&b8[4] = *(const float4*)&Ws[kk][64 + tx * 4];
#pragma unroll
            for (int ii = 0; ii < 4; ii++)
#pragma unroll
                for (int jj = 0; jj < 8; jj++)
                    acc[ii][jj] = fmaf(a[ii], b8[jj], acc[ii][jj]);
        }
        __syncthreads();
    }
#pragma unroll
    for (int ii = 0; ii < 4; ii++) {
        int i = ty * 4 + ii;
        float* op = out + (size_t)i * ostride + obase;
        *(float4*)&op[tx * 4] =
            make_float4(acc[ii][0] + bs[tx * 4 + 0], acc[ii][1] + bs[tx * 4 + 1],
                        acc[ii][2] + bs[tx * 4 + 2], acc[ii][3] + bs[tx * 4 + 3]);
        *(float4*)&op[64 + tx * 4] =
            make_float4(acc[ii][4] + bs[64 + tx * 4 + 0], acc[ii][5] + bs[64 + tx * 4 + 1],
                        acc[ii][6] + bs[64 + tx * 4 + 2], acc[ii][7] + bs[64 + tx * 4 + 3]);
    }
}

// =====================================================================
// Fused image-side precompute. grid 64.
// =====================================================================
__global__ __launch_bounds__(256) void img_kernel(
    const float* __restrict__ img_embed, const float* __restrict__ W_reduce_img,
    const float* __restrict__ b_reduce_img,
    float* __restrict__ base, float* __restrict__ iv)
{
    int i = blockIdx.x;
    int tid = threadIdx.x;
    __shared__ float row[Lsz];
    __shared__ float ps[4];
    for (int c = tid; c < Lsz; c += 256) {
        float s = 0.f;
        for (int r = 0; r < REG; r++) s += img_embed[((size_t)i * REG + r) * Lsz + c];
        row[c] = s * (1.f / (float)REG);
    }
    __syncthreads();
    float ss = 0.f;
    for (int c = tid; c < Lsz; c += 256) { float x = row[c]; ss = fmaf(x, x, ss); }
#pragma unroll
    for (int off = 32; off; off >>= 1) ss += __shfl_down(ss, off, 64);
    int lane = tid & 63, w = tid >> 6;
    if (lane == 0) ps[w] = ss;
    __syncthreads();
    float inv = 1.f / (sqrtf(ps[0] + ps[1] + ps[2] + ps[3]) + 1e-8f);
    for (int c = tid; c < Lsz; c += 256)
        iv[(size_t)i * Lsz + c] = row[c] * inv;
    for (int o = w * 32; o < w * 32 + 32; o++) {
        float a = 0.f;
        const float* wr = W_reduce_img + (size_t)o * Lsz + lane * 16;
        const float* rr = row + lane * 16;
#pragma unroll
        for (int u = 0; u < 16; u++) a = fmaf(wr[u], rr[u], a);
#pragma unroll
        for (int off = 32; off; off >>= 1) a += __shfl_down(a, off, 64);
        if (lane == 0) base[(size_t)i * Rsz + o] = a + b_reduce_img[o];
    }
}

// =====================================================================
// Pack gru_Whh_{f,b} [3072][1024] into MFMA A-frags, bf16 hi/lo.
// WFh/WFl: [dir][mstrip 192][k0 32][lane 64][elem 8]. grid (8,192,2).
// =====================================================================
__global__ __launch_bounds__(256) void packwhh_kernel(
    const float* __restrict__ Wf, const float* __restrict__ Wb,
    float* __restrict__ WFh_, float* __restrict__ WFl_)
{
    int tid = threadIdx.x;
    int l = tid & 63, wid = tid >> 6;
    int k0 = blockIdx.x * 4 + wid;
    int mstrip = blockIdx.y;
    int dir = blockIdx.z;
    const float* W = dir ? Wb : Wf;
    int row = mstrip * 16 + (l & 15);
    int col = k0 * 32 + (l >> 4) * 8;
    float v[8];
    *(float4*)&v[0] = *(const float4*)&W[(size_t)row * Lsz + col];
    *(float4*)&v[4] = *(const float4*)&W[(size_t)row * Lsz + col + 4];
    size_t off = ((size_t)(dir * 192 + mstrip) * 32 + k0) * 512 + l * 8;
    pack8(v, (ushort*)WFh_ + off, (ushort*)WFl_ + off);
}

// =====================================================================
// Pack WihAllT/WhhAllT [i][k 128][row 384] into per-image A-frags.
// GF: [i][mat][mstrip 24][kt 4][lane 64][elem 8]. grid (24,2,64).
// =====================================================================
__global__ __launch_bounds__(256) void packgenw_kernel(
    const float* __restrict__ WihAllT, const float* __restrict__ WhhAllT,
    float* __restrict__ GFh_, float* __restrict__ GFl_)
{
    int tid = threadIdx.x;
    int l = tid & 63, kt = tid >> 6;
    int mstrip = blockIdx.x;
    int mat = blockIdx.y;
    int i = blockIdx.z;
    const float* W = (mat ? WhhAllT : WihAllT) + (size_t)i * GENROWS;
    int row = mstrip * 16 + (l & 15);
    int kb = kt * 32 + (l >> 4) * 8;
    float v[8];
#pragma unroll
    for (int e = 0; e < 8; e++)
        v[e] = W[(size_t)(kb + e) * R3sz + row];
    size_t off = (((size_t)(i * 2 + mat) * 24 + mstrip) * 4 + kt) * 512 + l * 8;
    pack8(v, (ushort*)GFh_ + off, (ushort*)GFl_ + off);
}

// =====================================================================
// Pack capT2 [128][2048] into B-frags: [kt 4][ct' 128][lane 64][elem 8].
// grid (128). wave = kt.
// =====================================================================
__global__ __launch_bounds__(256) void packcap_kernel(
    const float* __restrict__ capT2, float* __restrict__ CFh_, float* __restrict__ CFl_)
{
    int tid = threadIdx.x;
    int l = tid & 63, kt = tid >> 6;
    int ctp = blockIdx.x;
    int col = ctp * 16 + (l & 15);
    int kb = kt * 32 + (l >> 4) * 8;
    float v[8];
#pragma unroll
    for (int e = 0; e < 8; e++)
        v[e] = capT2[(size_t)(kb + e) * NC + col];
    size_t off = ((size_t)kt * 128 + ctp) * 512 + l * 8;
    pack8(v, (ushort*)CFh_ + off, (ushort*)CFl_ + off);
}

// =====================================================================
// Pack gru_Wih_{f,b} [3072][300] into A-frags, K padded to 320.
// WihF: [dir][mstrip 192][kt 10][lane 64][elem 8]. grid (3,192,2).
// =====================================================================
__global__ __launch_bounds__(256) void packwih_kernel(
    const float* __restrict__ Wf, const float* __restrict__ Wb,
    float* __restrict__ Fh, float* __restrict__ Fl)
{
    int tid = threadIdx.x, l = tid & 63, wid = tid >> 6;
    int kt = blockIdx.x * 4 + wid;
    int m = blockIdx.y, dir = blockIdx.z;
    if (kt >= 10) return;
    const float* W = dir ? Wb : Wf;
    int row = m * 16 + (l & 15);
    int kb = kt * 32 + (l >> 4) * 8;
    float v[8];
#pragma unroll
    for (int e = 0; e < 8; e++) {
        int k = kb + e;
        v[e] = (k < DIN) ? W[(size_t)row * DIN + k] : 0.f;
    }
    size_t off = (((size_t)dir * 192 + m) * 10 + kt) * 512 + l * 8;
    pack8(v, (ushort*)Fh + off, (ushort*)Fl + off);
}

// =====================================================================
// Pack cap_embed [b][t][300] into B-frags [kt 10][ct 128][lane][8].
// grid (128, 3).
// =====================================================================
__global__ __launch_bounds__(256) void packcapb_kernel(
    const float* __restrict__ cap_embed, float* __restrict__ Fh, float* __restrict__ Fl)
{
    int tid = threadIdx.x, l = tid & 63, wid = tid >> 6;
    int ct = blockIdx.x;
    int kt = blockIdx.y * 4 + wid;
    if (kt >= 10) return;
    int c = ct * 16 + (l & 15), t = c >> 6, b = c & 63;
    int kb = kt * 32 + (l >> 4) * 8;
    float v[8];
#pragma unroll
    for (int e = 0; e < 8; e++) {
        int k = kb + e;
        v[e] = (k < DIN) ? cap_embed[((size_t)b * Tsz + t) * DIN + k] : 0.f;
    }
    size_t off = ((size_t)kt * 128 + ct) * 512 + l * 8;
    pack8(v, (ushort*)Fh + off, (ushort*)Fl + off);
}

// =====================================================================
// gi GEMM via MFMA bf16x3: giT2[n][c] = sum_k Wih[n][k]*cap[k][c] + bih[n].
// Block: 8 mstrips (2/wave) x 8 ctiles (B staged in LDS, shared by waves).
// grid (16 ctg, 24 mg, 2 dir).
// =====================================================================
__global__ __launch_bounds__(256) void gi_mfma(
    const float* __restrict__ WihF_h, const float* __restrict__ WihF_l,
    const float* __restrict__ capBF_h, const float* __restrict__ capBF_l,
    const float* __restrict__ bih_f, const float* __restrict__ bih_b,
    float* __restrict__ giT2_f, float* __restrict__ giT2_b)
{
    __shared__ __align__(16) ushort BsH[8][512];
    __shared__ __align__(16) ushort BsL[8][512];
    int tid = threadIdx.x, l = tid & 63, wid = tid >> 6;
    int ctg = blockIdx.x, mg = blockIdx.y, dir = blockIdx.z;
    int ct0 = ctg * 8;
    int m0 = mg * 8 + wid * 2;
    const ushort* AH = (const ushort*)WihF_h + (size_t)dir * (192 * 10 * 512);
    const ushort* AL = (const ushort*)WihF_l + (size_t)dir * (192 * 10 * 512);
    const ushort* BH = (const ushort*)capBF_h;
    const ushort* BL = (const ushort*)capBF_l;
    const float* bias = dir ? bih_b : bih_f;
    float* C = dir ? giT2_b : giT2_f;

    f32x4 acc[2][8];
#pragma unroll
    for (int m = 0; m < 2; m++)
#pragma unroll
        for (int ct = 0; ct < 8; ct++) acc[m][ct] = (f32x4){0.f, 0.f, 0.f, 0.f};

    for (int kt = 0; kt < 10; kt++) {
        __syncthreads();
#pragma unroll
        for (int u = 0; u < 2; u++) {
            int e = u * 256 + tid;       // e < 512
            int ct = e >> 6, p8 = (e & 63) * 8;
            *(uint4*)&BsH[ct][p8] = *(const uint4*)&BH[((size_t)kt * 128 + ct0 + ct) * 512 + p8];
            *(uint4*)&BsL[ct][p8] = *(const uint4*)&BL[((size_t)kt * 128 + ct0 + ct) * 512 + p8];
        }
        __syncthreads();
        bf16x8 Ah[2], Al[2];
#pragma unroll
        for (int m = 0; m < 2; m++) {
            size_t ao = ((size_t)(m0 + m) * 10 + kt) * 512 + l * 8;
            Ah[m] = *(const bf16x8*)(AH + ao);
            Al[m] = *(const bf16x8*)(AL + ao);
        }
#pragma unroll
        for (int ct = 0; ct < 8; ct++) {
            bf16x8 Bh = *(const bf16x8*)&BsH[ct][l * 8];
            bf16x8 Bl = *(const bf16x8*)&BsL[ct][l * 8];
#pragma unroll
            for (int m = 0; m < 2; m++) {
                acc[m][ct] = __builtin_amdgcn_mfma_f32_16x16x32_bf16(Ah[m], Bh, acc[m][ct], 0, 0, 0);
                acc[m][ct] = __builtin_amdgcn_mfma_f32_16x16x32_bf16(Ah[m], Bl, acc[m][ct], 0, 0, 0);
                acc[m][ct] = __builtin_amdgcn_mfma_f32_16x16x32_bf16(Al[m], Bh, acc[m][ct], 0, 0, 0);
            }
        }
    }
    int row4 = (l >> 4) * 4, col = l & 15;
#pragma unroll
    for (int m = 0; m < 2; m++) {
        int nb_ = (m0 + m) * 16 + row4;
#pragma unroll
        for (int r = 0; r < 4; r++) {
            float bv = bias[nb_ + r];
#pragma unroll
            for (int ct = 0; ct < 8; ct++)
                C[(size_t)(nb_ + r) * NC + (size_t)(ct0 + ct) * 16 + col] = acc[m][ct][r] + bv;
        }
    }
}

// =====================================================================
// Recurrence: MFMA bf16x3 GEMM + in-block reduce + gates, for steps
// [s0,s1). COOP=true: one cooperative launch runs all steps with
// grid.sync between them. COOP=false: launched once per step (fallback).
// grid 384 x 256thr:
//  bid<128: cap GRU. dir = bid>>6, j-strip js = bid&63 (16 h-dims).
//  bid>=128: gen GRU. i = (bid-128)>>2, strip-pair p = (bid-128)&3.
// =====================================================================
template <bool COOP>
__global__ __launch_bounds__(256) void rec_kernel(
    const float* __restrict__ WhhF_h, const float* __restrict__ WhhF_l,
    const float* __restrict__ WgenF_h, const float* __restrict__ WgenF_l,
    const float* __restrict__ capF_h, const float* __restrict__ capF_l,
    float* capHF_h, float* capHF_l,
    float* genHF_h, float* genHF_l,
    const float* __restrict__ giT2_f, const float* __restrict__ giT2_b,
    float* hfT, float* hbT,
    const float* __restrict__ bhh_f, const float* __restrict__ bhh_b,
    const float* __restrict__ bihAll, const float* __restrict__ bhhAll,
    float* hA, float* hB, float* hmaxT,
    int s0, int s1)
{
    __shared__ float red[48 * 256];
    int tid = threadIdx.x, l = tid & 63, wid = tid >> 6;
    int bid = blockIdx.x;

    for (int s = s0; s < s1; ++s) {
        int ping = (s & 1) ^ 1;   // read-side h-frag buffer
        int pong = s & 1;         // write-side

        if (bid < 128) {
            // ---------------- cap GRU ----------------
            int dir = bid >> 6, js = bid & 63;
            f32x4 acc[3][4];
#pragma unroll
            for (int g = 0; g < 3; g++)
#pragma unroll
                for (int ct = 0; ct < 4; ct++) acc[g][ct] = (f32x4){0.f, 0.f, 0.f, 0.f};

            if (s > 0) {
                const ushort* Wh = (const ushort*)WhhF_h + (size_t)dir * (192 * 32 * 512);
                const ushort* Wl = (const ushort*)WhhF_l + (size_t)dir * (192 * 32 * 512);
                const ushort* Hh = (const ushort*)capHF_h + (size_t)(dir * 2 + ping) * 65536;
                const ushort* Hl = (const ushort*)capHF_l + (size_t)(dir * 2 + ping) * 65536;
                for (int k8 = 0; k8 < 8; k8++) {
                    int k0 = wid * 8 + k8;
                    bf16x8 Bh[4], Bl[4], Ah[3], Al[3];
#pragma unroll
                    for (int ct = 0; ct < 4; ct++) {
                        size_t fo = ((size_t)k0 * 4 + ct) * 512 + l * 8;
                        Bh[ct] = *(const bf16x8*)(Hh + fo);
                        Bl[ct] = *(const bf16x8*)(Hl + fo);
                    }
#pragma unroll
                    for (int g = 0; g < 3; g++) {
                        size_t fo = ((size_t)(g * 64 + js) * 32 + k0) * 512 + l * 8;
                        Ah[g] = *(const bf16x8*)(Wh + fo);
                        Al[g] = *(const bf16x8*)(Wl + fo);
                    }
#pragma unroll
                    for (int g = 0; g < 3; g++)
#pragma unroll
                        for (int ct = 0; ct < 4; ct++)
                            acc[g][ct] = __builtin_amdgcn_mfma_f32_16x16x32_bf16(
                                Ah[g], Bh[ct], acc[g][ct], 0, 0, 0);
#pragma unroll
                    for (int g = 0; g < 3; g++)
#pragma unroll
                        for (int ct = 0; ct < 4; ct++)
                            acc[g][ct] = __builtin_amdgcn_mfma_f32_16x16x32_bf16(
                                Ah[g], Bl[ct], acc[g][ct], 0, 0, 0);
#pragma unroll
                    for (int g = 0; g < 3; g++)
#pragma unroll
                        for (int ct = 0; ct < 4; ct++)
                            acc[g][ct] = __builtin_amdgcn_mfma_f32_16x16x32_bf16(
                                Al[g], Bh[ct], acc[g][ct], 0, 0, 0);
                }
            }
#pragma unroll
            for (int g = 0; g < 3; g++)
#pragma unroll
                for (int ct = 0; ct < 4; ct++)
                    *(f32x4*)&red[((wid * 3 + g) * 4 + ct) * 256 + l * 4] = acc[g][ct];
            __syncthreads();

            const float* giT = dir ? giT2_b : giT2_f;
            float* hT        = dir ? hbT   : hfT;
            const float* bhh = dir ? bhh_b : bhh_f;
            int t  = dir ? (Tsz - 1 - s) : s;
            int tp = dir ? (t + 1) : (t - 1);
            ushort* Ch = (ushort*)capHF_h + (size_t)(dir * 2 + pong) * 65536;
            ushort* Cl = (ushort*)capHF_l + (size_t)(dir * 2 + pong) * 65536;
#pragma unroll
            for (int u = 0; u < 4; u++) {
                int e = u * 256 + tid;
                int jj = e >> 6, b = e & 63;
                int j = js * 16 + jj;
                float gh[3] = {0.f, 0.f, 0.f};
                if (s > 0) {
                    int lane_ = ((jj >> 2) << 4) | (b & 15);
                    int reg = jj & 3, ct = b >> 4;
#pragma unroll
                    for (int w = 0; w < 4; w++)
#pragma unroll
                        for (int g = 0; g < 3; g++)
                            gh[g] += red[((w * 3 + g) * 4 + ct) * 256 + lane_ * 4 + reg];
                }
                size_t gc = (size_t)t * 64 + b;
                float gr = giT[(size_t)j * NC + gc];
                float gz = giT[((size_t)Lsz + j) * NC + gc];
                float gn = giT[((size_t)2 * Lsz + j) * NC + gc];
                float hp = (s > 0) ? hT[((size_t)tp * Lsz + j) * Bsz + b] : 0.f;
                float r = sigf(gr + gh[0] + bhh[j]);
                float z = sigf(gz + gh[1] + bhh[Lsz + j]);
                float n = tanhf(gn + r * (gh[2] + bhh[2 * Lsz + j]));
                float h = (1.f - z) * n + z * hp;
                hT[((size_t)t * Lsz + j) * Bsz + b] = h;
                size_t fo = hfrag_off(j, b);
                ushort hb = f2bf(h);
                Ch[fo] = hb;
                Cl[fo] = f2bf(h - bf2f(hb));
            }
        } else {
            // ---------------- gen GRU ----------------
            int g2 = bid - 128;
            int i = g2 >> 2;
            int p = g2 & 3;
            int mat = wid & 1;    // 0 = ih, 1 = hh
            int sl = wid >> 1;    // strip within pair
            int strip = p * 2 + sl;
            float* hcurT = (s & 1) ? hB : hA;
            const float* hprevT = (s & 1) ? hA : hB;
            f32x4 acc[3][4];
#pragma unroll
            for (int g = 0; g < 3; g++)
#pragma unroll
                for (int ct = 0; ct < 4; ct++) acc[g][ct] = (f32x4){0.f, 0.f, 0.f, 0.f};

            if (mat == 0 || s > 0) {
                const ushort* Ahp = (const ushort*)WgenF_h + (size_t)(i * 2 + mat) * 96 * 512;
                const ushort* Alp = (const ushort*)WgenF_l + (size_t)(i * 2 + mat) * 96 * 512;
                const ushort* Bhp;
                const ushort* Blp;
                if (mat == 0) {
                    Bhp = (const ushort*)capF_h;
                    Blp = (const ushort*)capF_l;
                } else {
                    Bhp = (const ushort*)genHF_h + (size_t)(ping * 64 + i) * 8192;
                    Blp = (const ushort*)genHF_l + (size_t)(ping * 64 + i) * 8192;
                }
                for (int kt = 0; kt < 4; kt++) {
                    bf16x8 Bh[4], Bl[4], Ah[3], Al[3];
#pragma unroll
                    for (int ct = 0; ct < 4; ct++) {
                        size_t fo = (mat == 0)
                            ? ((size_t)kt * 128 + s * 4 + ct) * 512 + l * 8
                            : ((size_t)kt * 4 + ct) * 512 + l * 8;
                        Bh[ct] = *(const bf16x8*)(Bhp + fo);
                        Bl[ct] = *(const bf16x8*)(Blp + fo);
                    }
#pragma unroll
                    for (int g = 0; g < 3; g++) {
                        size_t fo = ((size_t)(g * 8 + strip) * 4 + kt) * 512 + l * 8;
                        Ah[g] = *(const bf16x8*)(Ahp + fo);
                        Al[g] = *(const bf16x8*)(Alp + fo);
                    }
#pragma unroll
                    for (int g = 0; g < 3; g++)
#pragma unroll
                        for (int ct = 0; ct < 4; ct++)
                            acc[g][ct] = __builtin_amdgcn_mfma_f32_16x16x32_bf16(
                                Ah[g], Bh[ct], acc[g][ct], 0, 0, 0);
#pragma unroll
                    for (int g = 0; g < 3; g++)
#pragma unroll
                        for (int ct = 0; ct < 4; ct++)
                            acc[g][ct] = __builtin_amdgcn_mfma_f32_16x16x32_bf16(
                                Ah[g], Bl[ct], acc[g][ct], 0, 0, 0);
#pragma unroll
                    for (int g = 0; g < 3; g++)
#pragma unroll
                        for (int ct = 0; ct < 4; ct++)
                            acc[g][ct] = __builtin_amdgcn_mfma_f32_16x16x32_bf16(
                                Al[g], Bh[ct], acc[g][ct], 0, 0, 0);
                }
            }
#pragma unroll
            for (int g = 0; g < 3; g++)
#pragma unroll
                for (int ct = 0; ct < 4; ct++)
                    *(f32x4*)&red[(((sl * 2 + mat) * 3 + g) * 4 + ct) * 256 + l * 4] = acc[g][ct];
            __syncthreads();

            const float* bih = bihAll + (size_t)i * R3sz;
            const float* bhh = bhhAll + (size_t)i * R3sz;
            ushort* Gh = (ushort*)genHF_h + (size_t)(pong * 64 + i) * 8192;
            ushort* Gl = (ushort*)genHF_l + (size_t)(pong * 64 + i) * 8192;
#pragma unroll
            for (int u = 0; u < 8; u++) {
                int e = u * 256 + tid;
                int sl2 = e >> 10;
                int jj = (e >> 6) & 15;
                int b = e & 63;
                int j = (p * 2 + sl2) * 16 + jj;
                int lane_ = ((jj >> 2) << 4) | (b & 15);
                int reg = jj & 3, ct = b >> 4;
                float sih[3], shh[3];
#pragma unroll
                for (int g = 0; g < 3; g++) {
                    sih[g] = red[(((sl2 * 2 + 0) * 3 + g) * 4 + ct) * 256 + lane_ * 4 + reg];
                    shh[g] = (s > 0)
                        ? red[(((sl2 * 2 + 1) * 3 + g) * 4 + ct) * 256 + lane_ * 4 + reg]
                        : 0.f;
                }
                float r = sigf(sih[0] + bih[j] + shh[0] + bhh[j]);
                float z = sigf(sih[1] + bih[Rsz + j] + shh[1] + bhh[Rsz + j]);
                float n = tanhf(sih[2] + bih[2 * Rsz + j] + r * (shh[2] + bhh[2 * Rsz + j]));
                float hp = (s > 0) ? hprevT[((size_t)i * Rsz + j) * Bsz + b] : 0.f;
                float h = (1.f - z) * n + z * hp;
                size_t idx = ((size_t)i * Rsz + j) * Bsz + b;
                hcurT[idx] = h;
                hmaxT[idx] = (s == 0) ? h : fmaxf(hmaxT[idx], h);
                size_t fo = hfrag_off(j, b);
                ushort hb = f2bf(h);
                Gh[fo] = hb;
                Gl[fo] = f2bf(h - bf2f(hb));
            }
        }

        if constexpr (COOP) {
            __threadfence();
            cg::this_grid().sync();
        }
    }
}

// =====================================================================
// txt = (hf+hb)/2 -> row-major txt [b][t][c] AND column txtT [c][t*64+b].
// =====================================================================
__global__ __launch_bounds__(256) void txt_combine(
    const float* __restrict__ hfT, const float* __restrict__ hbT,
    float* __restrict__ txt, float* __restrict__ txtT)
{
    __shared__ float s[64][65];
    int t = blockIdx.x;
    int c0 = blockIdx.y * 64;
    int tid = threadIdx.x;
#pragma unroll
    for (int l = 0; l < 16; l++) {
        int e = l * 256 + tid;
        int cc = e >> 6, b = e & 63;
        size_t idx = ((size_t)t * Lsz + c0 + cc) * Bsz + b;
        s[cc][b] = 0.5f * (hfT[idx] + hbT[idx]);
    }
    __syncthreads();
#pragma unroll
    for (int l = 0; l < 16; l++) {
        int e = l * 256 + tid;
        int b = e >> 6, cc = e & 63;
        txt[((size_t)b * Tsz + t) * Lsz + c0 + cc] = s[cc][b];
    }
#pragma unroll
    for (int l = 0; l < 16; l++) {
        int e = l * 256 + tid;
        int cc = e >> 6, b = e & 63;
        txtT[(size_t)(c0 + cc) * NC + t * 64 + b] = s[cc][b];
    }
}

// =====================================================================
// Self-attention. v comes as 2 K-split partials vP[z][c][t*64+b].
// =====================================================================
__global__ __launch_bounds__(256) void attn_kernel(
    const float* __restrict__ q, const float* __restrict__ kmat,
    const float* __restrict__ vP, const float* __restrict__ sa_bv,
    const float* __restrict__ txt,
    const float* __restrict__ gamma_p, float* __restrict__ xattn)
{
    __shared__ float qs[32][129];
    __shared__ float ks[32][129];
    __shared__ float Sc[32][33];
    __shared__ float vs[128][33];
    int b = blockIdx.x;
    int c0 = blockIdx.y * 128;
    int tid = threadIdx.x;
    for (int e = tid; e < Tsz * Rsz; e += 256) {
        qs[e >> 7][e & 127] = q[(size_t)b * Tsz * Rsz + e];
        ks[e >> 7][e & 127] = kmat[(size_t)b * Tsz * Rsz + e];
    }
    for (int e = tid; e < 128 * 32; e += 256) {
        int cc = e >> 5, ss = e & 31;
        size_t base = (size_t)(c0 + cc) * NC + ss * 64 + b;
        float v = sa_bv[c0 + cc];
#pragma unroll
        for (int z = 0; z < 2; z++)
            v += vP[(size_t)z * Lsz * NC + base];
        vs[cc][ss] = v;
    }
    __syncthreads();
    for (int e = tid; e < Tsz * Tsz; e += 256) {
        int t = e >> 5, ss = e & 31;
        float acc = 0.f;
#pragma unroll 4
        for (int o = 0; o < Rsz; o++) acc = fmaf(qs[t][o], ks[ss][o], acc);
        Sc[t][ss] = acc;
    }
    __syncthreads();
    if (tid < 32) {
        int t = tid;
        float mx = -1e30f;
#pragma unroll
        for (int ss = 0; ss < 32; ss++) mx = fmaxf(mx, Sc[t][ss]);
        float sum = 0.f;
        float ex[32];
#pragma unroll
        for (int ss = 0; ss < 32; ss++) { ex[ss] = __expf(Sc[t][ss] - mx); sum += ex[ss]; }
        float inv = 1.f / sum;
#pragma unroll
        for (int ss = 0; ss < 32; ss++) Sc[t][ss] = ex[ss] * inv;
    }
    __syncthreads();
    float gamma = *gamma_p;
    for (int e = tid; e < Tsz * 128; e += 256) {
        int tt = e >> 7, cc = e & 127;
        float acc = 0.f;
#pragma unroll 8
        for (int ss = 0; ss < Tsz; ss++)
            acc = fmaf(Sc[tt][ss], vs[cc][ss], acc);
        size_t oidx = ((size_t)b * Tsz + tt) * Lsz + c0 + cc;
        xattn[oidx] = gamma * acc + txt[oidx];
    }
}

// ---------------- length-masked mean pool, grid (64,4) ----------------
__global__ __launch_bounds__(256) void pool_kernel(
    const float* __restrict__ xattn, const int* __restrict__ lens,
    float* __restrict__ txt_embed)
{
    int b = blockIdx.x;
    int c = blockIdx.y * 256 + threadIdx.x;
    int len = lens[b];
    float s = 0.f;
    for (int t = 0; t < len; t++) s += xattn[((size_t)b * Tsz + t) * Lsz + c];
    txt_embed[(size_t)b * Lsz + c] = s / (float)len;
}

// =====================================================================
// base_fcT[n][b] = dot(txt_emb[b][:], W_txt_fc[n][0:1024]). grid 256.
// =====================================================================
__global__ __launch_bounds__(256) void basefc_kernel(
    const float* __restrict__ temb, const float* __restrict__ W,
    float* __restrict__ outT)
{
    int lane = threadIdx.x & 63, w = threadIdx.x >> 6;
    int n = blockIdx.x * 4 + w;
    const float* wr = W + (size_t)n * (Rsz + Lsz) + lane * 16;
    float wv[16];
#pragma unroll
    for (int u = 0; u < 4; u++) *(float4*)&wv[u * 4] = *(const float4*)&wr[u * 4];
    for (int b = 0; b < Bsz; b++) {
        const float* te = temb + (size_t)b * Lsz + lane * 16;
        float tv[16];
#pragma unroll
        for (int u = 0; u < 4; u++) *(float4*)&tv[u * 4] = *(const float4*)&te[u * 4];
        float a = 0.f;
#pragma unroll
        for (int u = 0; u < 16; u++) a = fmaf(wv[u], tv[u], a);
#pragma unroll
        for (int off = 32; off; off >>= 1) a += __shfl_down(a, off, 64);
        if (lane == 0) outT[(size_t)n * Bsz + b] = a;
    }
}

// ---- hmaxT [i][j][b] -> hstdT [j][i*64+b], coalesced permute. grid 64 ----
__global__ __launch_bounds__(256) void hstdT_kernel(
    const float* __restrict__ hmaxT, float* __restrict__ hstdT)
{
    int i = blockIdx.x, tid = threadIdx.x;
    int b = tid & 63, j0 = tid >> 6;
#pragma unroll
    for (int l = 0; l < 32; l++) {
        int j = l * 4 + j0;
        hstdT[(size_t)j * 4096 + i * 64 + b] = hmaxT[((size_t)i * Rsz + j) * Bsz + b];
    }
}

// =====================================================================
// sims partial reduce: column layouts, fully coalesced. grid (64, 4).
// =====================================================================
__global__ __launch_bounds__(256) void sims_part(
    const float* __restrict__ fcT, const float* __restrict__ base_fcT,
    const float* __restrict__ bfc, const float* __restrict__ iv,
    float* __restrict__ accA, float* __restrict__ accB)
{
    int i = blockIdx.x, cs = blockIdx.y;
    int tid = threadIdx.x;
    int w = tid >> 6, b = tid & 63;
    float s1 = 0.f, s2 = 0.f;
    for (int u = 0; u < 64; u++) {
        int c = cs * 256 + w * 64 + u;
        float f = fcT[(size_t)c * 4096 + i * 64 + b] + base_fcT[(size_t)c * Bsz + b] + bfc[c];
        s1 = fmaf(f, f, s1);
        s2 = fmaf(f, iv[(size_t)i * Lsz + c], s2);
    }
    int m = i * 64 + b;
    atomicAdd(&accA[m], s1);
    atomicAdd(&accB[m], s2);
}

__global__ __launch_bounds__(256) void sims_final(
    const float* __restrict__ accA, const float* __restrict__ accB,
    float* __restrict__ out)
{
    int m = blockIdx.x * 256 + threadIdx.x;
    out[m] = accB[m] / (sqrtf(accA[m]) + 1e-8f);
}

// =====================================================================
extern "C" void kernel_launch(void* const* d_in, const int* in_sizes, int n_in,
                              void* d_out, int out_size, void* d_ws, size_t ws_size,
                              hipStream_t stream)
{
    const float* img_embed    = (const float*)d_in[0];
    const float* cap_embed    = (const float*)d_in[1];
    const int*   lens         = (const int*)d_in[2];
    const float* W_reduce_img = (const float*)d_in[3];
    const float* b_reduce_img = (const float*)d_in[4];
    const float* W_reduce_txt = (const float*)d_in[5];
    const float* b_reduce_txt = (const float*)d_in[6];
    const float* gru_Wih_f    = (const float*)d_in[7];
    const float* gru_Whh_f    = (const float*)d_in[8];
    const float* gru_bih_f    = (const float*)d_in[9];
    const float* gru_bhh_f    = (const float*)d_in[10];
    const float* gru_Wih_b    = (const float*)d_in[11];
    const float* gru_Whh_b    = (const float*)d_in[12];
    const float* gru_bih_b    = (const float*)d_in[13];
    const float* gru_bhh_b    = (const float*)d_in[14];
    const float* sa_Wq        = (const float*)d_in[15];
    const float* sa_bq        = (const float*)d_in[16];
    const float* sa_Wk        = (const float*)d_in[17];
    const float* sa_bk        = (const float*)d_in[18];
    const float* sa_Wv        = (const float*)d_in[19];
    const float* sa_bv        = (const float*)d_in[20];
    const float* sa_gamma     = (const float*)d_in[21];
    const float* gen_Wih      = (const float*)d_in[22];
    const float* gen_bih      = (const float*)d_in[23];
    const float* gen_Whh      = (const float*)d_in[24];
    const float* gen_bhh      = (const float*)d_in[25];
    const float* gen_Wbih     = (const float*)d_in[26];
    const float* gen_bbih     = (const float*)d_in[27];
    const float* gen_Wbhh     = (const float*)d_in[28];
    const float* gen_bbhh     = (const float*)d_in[29];
    const float* W_txt_fc     = (const float*)d_in[30];
    const float* b_txt_fc     = (const float*)d_in[31];

    float* ws = (float*)d_ws;
    size_t off = 0;
    auto alloc = [&](size_t n) { float* p = ws + off; off += n; return p; };
    float* giT2_f   = alloc((size_t)H3sz * NC);
    float* giT2_b   = alloc((size_t)H3sz * NC);
    float* hfT      = alloc((size_t)Tsz * Lsz * Bsz);
    float* hbT      = alloc((size_t)Tsz * Lsz * Bsz);
    float* capTr    = alloc((size_t)KPAD * NC);
    float* capT2    = alloc((size_t)Rsz * NC);
    float* txt      = alloc((size_t)Bsz * Tsz * Lsz);
    float* txtT     = alloc((size_t)Lsz * NC);
    float* qbuf     = alloc((size_t)Bsz * Tsz * Rsz);
    float* kbuf     = alloc((size_t)Bsz * Tsz * Rsz);
    // Big pool: during the loop it holds the bf16 hi/lo weight frags;
    // after the loop the attention/fc buffers reuse it (disjoint lifetimes).
    float* pool     = alloc((size_t)12582912);
    float* WhhFh  = pool;                  // 3,145,728 floats (bf16 x2 per float)
    float* WhhFl  = pool + 3145728;
    float* WgenFh = pool + 6291456;
    float* WgenFl = pool + 9437184;
    float* qP  = pool;                     // 2,097,152
    float* kP  = pool + 2097152;           // 2,097,152
    float* vP  = pool + 4194304;           // 4,194,304
    float* fcT = pool + 8388608;           // 4,194,304
    float* xattn    = alloc((size_t)Bsz * Tsz * Lsz);
    float* txt_emb  = alloc((size_t)Bsz * Lsz);
    float* base     = alloc((size_t)Bsz * Rsz);
    float* iv       = alloc((size_t)Bsz * Lsz);
    float* WihAllT  = alloc((size_t)Bsz * GENROWS);
    float* WhhAllT  = alloc((size_t)Bsz * GENROWS);
    float* WihFh    = alloc((size_t)983040);   // Wih A-frags hi (bf16, K=320)
    float* WihFl    = alloc((size_t)983040);
    float* capBFh   = alloc((size_t)327680);   // cap_embed B-frags hi
    float* capBFl   = alloc((size_t)327680);
    float* WrtT     = alloc((size_t)KPAD * Rsz);
    float* WvT      = alloc((size_t)Lsz * Lsz);
    float* WqT      = alloc((size_t)Lsz * Rsz);
    float* WkT      = alloc((size_t)Lsz * Rsz);
    float* WfcT     = alloc((size_t)Rsz * Lsz);
    float* bihAll   = alloc((size_t)Bsz * R3sz);
    float* bhhAll   = alloc((size_t)Bsz * R3sz);
    float* hA       = alloc((size_t)Bsz * Rsz * Bsz);
    float* hB       = alloc((size_t)Bsz * Rsz * Bsz);
    float* hmaxT    = alloc((size_t)Bsz * Rsz * Bsz);
    float* hstdT    = alloc((size_t)Rsz * Bsz * Bsz);
    float* base_fcT = alloc((size_t)Lsz * Bsz);
    float* accA     = alloc(4096);
    float* accB     = alloc(4096);
    float* capFh    = alloc(131072);   // capT2 B-frags hi (bf16)
    float* capFl    = alloc(131072);
    float* capHFh   = alloc(131072);   // cap h B-frags [dir][ping]
    float* capHFl   = alloc(131072);
    float* genHFh   = alloc(524288);   // gen h B-frags [ping][i]
    float* genHFl   = alloc(524288);

    // 0) zero the sims accumulators
    hipMemsetAsync(accA, 0, 2 * 4096 * sizeof(float), stream);

    // 1) one-time transposes / packs
    transp_kernel<<<dim3(5, 2), 256, 0, stream>>>(W_reduce_txt, WrtT, Rsz, DIN, KPAD, DIN, 0);
    transp_kernel<<<dim3(16, 16), 256, 0, stream>>>(sa_Wv, WvT, Lsz, Lsz, Lsz, Lsz, 0);
    transp_kernel<<<dim3(16, 2), 256, 0, stream>>>(sa_Wq, WqT, Rsz, Lsz, Lsz, Lsz, 0);
    transp_kernel<<<dim3(16, 2), 256, 0, stream>>>(sa_Wk, WkT, Rsz, Lsz, Lsz, Lsz, 0);
    transp_kernel<<<dim3(2, 16), 256, 0, stream>>>(W_txt_fc, WfcT, Lsz, Rsz, Rsz, Rsz + Lsz, Lsz);
    captr_kernel<<<dim3(32, 5), 256, 0, stream>>>(cap_embed, capTr);
    packwih_kernel<<<dim3(3, 192, 2), 256, 0, stream>>>(gru_Wih_f, gru_Wih_b, WihFh, WihFl);
    packcapb_kernel<<<dim3(128, 3), 256, 0, stream>>>(cap_embed, capBFh, capBFl);

    // 2) image-side precompute + generated weights, then frag-pack weights
    img_kernel<<<64, 256, 0, stream>>>(img_embed, W_reduce_img, b_reduce_img, base, iv);
    genw_gemm<<<dim3(3, 129, 2), 256, 0, stream>>>(gen_Wih, gen_bih, gen_Whh, gen_bhh,
        gen_Wbih, gen_bbih, gen_Wbhh, gen_bbhh, base, WihAllT, WhhAllT, bihAll, bhhAll);
    packwhh_kernel<<<dim3(8, 192, 2), 256, 0, stream>>>(gru_Whh_f, gru_Whh_b, WhhFh, WhhFl);
    packgenw_kernel<<<dim3(24, 2, 64), 256, 0, stream>>>(WihAllT, WhhAllT, WgenFh, WgenFl);

    // 3) gi (both dirs, MFMA) + cap_reduced + its frag pack
    gi_mfma<<<dim3(16, 24, 2), 256, 0, stream>>>(WihFh, WihFl, capBFh, capBFl,
        gru_bih_f, gru_bih_b, giT2_f, giT2_b);
    gemm_tt<<<dim3(16, 1, 1), 256, 0, stream>>>(WrtT, WrtT, capTr,
        b_reduce_txt, b_reduce_txt, capT2, capT2, Rsz);
    packcap_kernel<<<128, 256, 0, stream>>>(capT2, capFh, capFl);

    // 4) recurrences: one cooperative kernel for all 32 steps
    //    (fallback to per-step launches if co-residency is unavailable)
    {
        int s0 = 0, s1 = Tsz;
        void* kargs[] = {
            (void*)&WhhFh, (void*)&WhhFl, (void*)&WgenFh, (void*)&WgenFl,
            (void*)&capFh, (void*)&capFl, (void*)&capHFh, (void*)&capHFl,
            (void*)&genHFh, (void*)&genHFl, (void*)&giT2_f, (void*)&giT2_b,
            (void*)&hfT, (void*)&hbT, (void*)&gru_bhh_f, (void*)&gru_bhh_b,
            (void*)&bihAll, (void*)&bhhAll, (void*)&hA, (void*)&hB,
            (void*)&hmaxT, (void*)&s0, (void*)&s1
        };
        int nb = 0;
        hipOccupancyMaxActiveBlocksPerMultiprocessor(&nb, rec_kernel<true>, 256, 0);
        if (nb >= 2) {
            hipLaunchCooperativeKernel((void*)rec_kernel<true>, dim3(384), dim3(256),
                                       kargs, 0, stream);
        } else {
            for (int s = 0; s < Tsz; s++)
                rec_kernel<false><<<384, 256, 0, stream>>>(WhhFh, WhhFl, WgenFh, WgenFl,
                    capFh, capFl, capHFh, capHFl, genHFh, genHFl, giT2_f, giT2_b,
                    hfT, hbT, gru_bhh_f, gru_bhh_b, bihAll, bhhAll, hA, hB, hmaxT,
                    s, s + 1);
        }
    }
    hstdT_kernel<<<64, 256, 0, stream>>>(hmaxT, hstdT);

    // 5) combine + self-attention (q/k/v all via K-split TT GEMMs)
    txt_combine<<<dim3(32, 16), 256, 0, stream>>>(hfT, hbT, txt, txtT);
    gemm_qk<<<dim3(16, 2, 8), 256, 0, stream>>>(WqT, WkT, txtT, qP, kP);
    gemm_ttp<<<dim3(16, 8, 2), 256, 0, stream>>>(WvT, txtT, vP, Lsz, NC, 512);
    qkc_kernel<<<dim3(32, 2), 256, 0, stream>>>(qP, kP, sa_bq, sa_bk, qbuf, kbuf);
    attn_kernel<<<dim3(64, 8), 256, 0, stream>>>(qbuf, kbuf, vP, sa_bv, txt,
        sa_gamma, xattn);

    // 6) pool + image-independent FC part (transposed output)
    pool_kernel<<<dim3(64, 4), 256, 0, stream>>>(xattn, lens, txt_emb);
    basefc_kernel<<<256, 256, 0, stream>>>(txt_emb, W_txt_fc, base_fcT);

    // 7) fc delta (column layout) + sims partial/final
    gemm_ttp<<<dim3(32, 8, 1), 256, 0, stream>>>(WfcT, hstdT, fcT, Lsz, 4096, Rsz);
    sims_part<<<dim3(64, 4), 256, 0, stream>>>(fcT, base_fcT, b_txt_fc, iv, accA, accB);
    sims_final<<<16, 256, 0, stream>>>(accA, accB, (float*)d_out);
}

// Round 3
// 1260.897 us; speedup vs baseline: 1.3114x; 1.3114x over previous
//
#include <hip/hip_runtime.h>
#include <math.h>

// ---------------- problem constants ----------------
#define Lsz   1024
#define Tsz   32
#define Bsz   64
#define DIN   300
#define REG   36
#define Rsz   128
#define R3sz  384
#define H3sz  3072
#define GENROWS 49152   // R3sz * Rsz
#define NC    2048      // caption columns c = t*64 + b
#define KPAD  304       // DIN padded to /16 (fp32 path)

typedef __attribute__((ext_vector_type(8))) short bf16x8;
typedef __attribute__((ext_vector_type(4))) float f32x4;

__device__ __forceinline__ float sigf(float x) { return 1.f / (1.f + __expf(-x)); }

// f32 -> bf16 (RNE) bit trick; and back.
__device__ __forceinline__ ushort f2bf(float x) {
    unsigned u = __float_as_uint(x);
    unsigned r = (u + 0x7fffu + ((u >> 16) & 1u)) >> 16;
    return (ushort)r;
}
__device__ __forceinline__ float bf2f(ushort h) {
    return __uint_as_float((unsigned)h << 16);
}

// Fragment layout for mfma_f32_16x16x32_bf16 operands:
//   A[m][k]: m = lane&15, k-slot = (lane>>4)*8 + elem   (contiguous 8)
//   B[k][n]: n = lane&15, same k-slot structure.
// Both packs use the same slot->k map, so the map cancels in the dot.
// C/D (measured, m89): col = lane&15, row = (lane>>4)*4 + reg.
// Frag storage: frag_idx*512 + lane*8 + elem (ushort units; 1 KB/frag).

// h-fragment byte-slot for B-operand pack: k = h-dim, b = batch col.
__device__ __forceinline__ size_t hfrag_off(int k, int b) {
    return (((size_t)(k >> 5) * 4 + (b >> 4)) * 64 +
            ((((k >> 3) & 3) << 4) | (b & 15))) * 8 + (k & 7);
}

__device__ __forceinline__ void pack8(const float* v, ushort* dsth, ushort* dstl) {
    unsigned hw[4], lw[4];
#pragma unroll
    for (int e2 = 0; e2 < 4; e2++) {
        ushort h0 = f2bf(v[2 * e2]);
        ushort h1 = f2bf(v[2 * e2 + 1]);
        ushort l0 = f2bf(v[2 * e2] - bf2f(h0));
        ushort l1 = f2bf(v[2 * e2 + 1] - bf2f(h1));
        hw[e2] = (unsigned)h0 | ((unsigned)h1 << 16);
        lw[e2] = (unsigned)l0 | ((unsigned)l1 << 16);
    }
    *(uint4*)dsth = make_uint4(hw[0], hw[1], hw[2], hw[3]);
    *(uint4*)dstl = make_uint4(lw[0], lw[1], lw[2], lw[3]);
}

// =====================================================================
// Generic transpose: out[c*R + r] = in[r*lda + woff + c], c < Cin,
// zero-pad c in [Cin, Cpad). grid (ceil(Cpad/64), ceil(R/64)).
// =====================================================================
__global__ __launch_bounds__(256) void transp_kernel(
    const float* __restrict__ in, float* __restrict__ out,
    int R, int Cin, int Cpad, int lda, int woff)
{
    __shared__ float s[64][65];
    int c0 = blockIdx.x * 64, r0 = blockIdx.y * 64;
    int tid = threadIdx.x;
#pragma unroll
    for (int l = 0; l < 16; l++) {
        int e = l * 256 + tid;
        int rr = e >> 6, cc = e & 63;
        int r = r0 + rr, c = c0 + cc;
        s[rr][cc] = (r < R && c < Cin) ? in[(size_t)r * lda + woff + c] : 0.f;
    }
    __syncthreads();
#pragma unroll
    for (int l = 0; l < 16; l++) {
        int e = l * 256 + tid;
        int cc = e >> 6, rr = e & 63;
        int c = c0 + cc, r = r0 + rr;
        if (c < Cpad && r < R) out[(size_t)c * R + r] = s[rr][cc];
    }
}

// =====================================================================
// cap_embed [b][t][d] -> capTr [k][t*64+b], k zero-padded to 304.
// =====================================================================
__global__ __launch_bounds__(256) void captr_kernel(
    const float* __restrict__ cap_embed, float* __restrict__ capTr)
{
    __shared__ float s[64][65];
    int t = blockIdx.x, kc = blockIdx.y;
    int tid = threadIdx.x;
#pragma unroll
    for (int l = 0; l < 16; l++) {
        int e = l * 256 + tid;
        int b = e >> 6, kk = e & 63;
        int k = kc * 64 + kk;
        s[b][kk] = (k < DIN) ? cap_embed[((size_t)b * Tsz + t) * DIN + k] : 0.f;
    }
    __syncthreads();
#pragma unroll
    for (int l = 0; l < 16; l++) {
        int e = l * 256 + tid;
        int kk = e >> 6, b = e & 63;
        int k = kc * 64 + kk;
        if (k < KPAD)
            capTr[(size_t)k * NC + t * 64 + b] = s[b][kk];
    }
}

// =====================================================================
// All-transposed GEMM (fp32): C[n][c] = sum_k WT[k][n]*X[k][c] + bias[n].
// Only used for the small cap_reduced GEMM now.
// =====================================================================
__global__ __launch_bounds__(256) void gemm_tt(
    const float* __restrict__ WT1, const float* __restrict__ WT2,
    const float* __restrict__ X,
    const float* __restrict__ b1, const float* __restrict__ b2,
    float* __restrict__ C1, float* __restrict__ C2, int Ntot)
{
    const float* WT = blockIdx.z ? WT2 : WT1;
    const float* bias = blockIdx.z ? b2 : b1;
    float* C = blockIdx.z ? C2 : C1;
    __shared__ float Ws[16][132];
    __shared__ float Xs[16][132];
    int tid = threadIdx.x, tx = tid & 15, ty = tid >> 4;
    int c0 = blockIdx.x * 128, n0 = blockIdx.y * 128;
    float acc[8][8];
#pragma unroll
    for (int i = 0; i < 8; i++)
#pragma unroll
        for (int j = 0; j < 8; j++) acc[i][j] = 0.f;

    for (int k0 = 0; k0 < KPAD; k0 += 16) {
#pragma unroll
        for (int l = 0; l < 2; l++) {
            int e = l * 256 + tid;
            int l16 = e & 15, seg = e >> 4;
            int kk = seg & 15, half = seg >> 4;
            int col = half * 64 + l16 * 4;
            *(float4*)&Ws[kk][col] = *(const float4*)&WT[(size_t)(k0 + kk) * Ntot + n0 + col];
            *(float4*)&Xs[kk][col] = *(const float4*)&X[(size_t)(k0 + kk) * NC + c0 + col];
        }
        __syncthreads();
#pragma unroll
        for (int kk = 0; kk < 16; kk++) {
            float a[8], x[8];
            *(float4*)&a[0] = *(const float4*)&Ws[kk][ty * 8];
            *(float4*)&a[4] = *(const float4*)&Ws[kk][ty * 8 + 4];
            *(float4*)&x[0] = *(const float4*)&Xs[kk][tx * 4];
            *(float4*)&x[4] = *(const float4*)&Xs[kk][64 + tx * 4];
#pragma unroll
            for (int i = 0; i < 8; i++)
#pragma unroll
                for (int j = 0; j < 8; j++) acc[i][j] = fmaf(a[i], x[j], acc[i][j]);
        }
        __syncthreads();
    }
#pragma unroll
    for (int i = 0; i < 8; i++) {
        int n = n0 + ty * 8 + i;
        float bv = bias[n];
        *(float4*)&C[(size_t)n * NC + c0 + tx * 4] =
            make_float4(acc[i][0] + bv, acc[i][1] + bv, acc[i][2] + bv, acc[i][3] + bv);
        *(float4*)&C[(size_t)n * NC + c0 + 64 + tx * 4] =
            make_float4(acc[i][4] + bv, acc[i][5] + bv, acc[i][6] + bv, acc[i][7] + bv);
    }
}

// =====================================================================
// qk combine: transpose single partial + bias to [b][t][o] layout.
// grid (32 t, 2 qk), 256 thr.
// =====================================================================
__global__ __launch_bounds__(256) void qkc_kernel(
    const float* __restrict__ qkbuf,
    const float* __restrict__ sa_bq, const float* __restrict__ sa_bk,
    float* __restrict__ qbuf, float* __restrict__ kbuf)
{
    __shared__ float s[128][65];
    int t = blockIdx.x, qk = blockIdx.y;
    const float* P = qkbuf + (size_t)qk * Rsz * NC;
    const float* bias = qk ? sa_bk : sa_bq;
    float* dst = qk ? kbuf : qbuf;
    int tid = threadIdx.x;
    for (int e = tid; e < 128 * 64; e += 256) {
        int o = e >> 6, b = e & 63;
        s[o][b] = P[(size_t)o * NC + t * 64 + b];
    }
    __syncthreads();
    for (int e = tid; e < 128 * 64; e += 256) {
        int b = e >> 7, o = e & 127;
        dst[((size_t)b * Tsz + t) * Rsz + o] = s[o][b] + bias[o];
    }
}

// =====================================================================
// Generated weights GEMM -> WihAllT/WhhAllT [i][k][row]. grid (3,129,2).
// =====================================================================
__global__ __launch_bounds__(256) void genw_gemm(
    const float* __restrict__ gen_Wih, const float* __restrict__ gen_bih,
    const float* __restrict__ gen_Whh, const float* __restrict__ gen_bhh,
    const float* __restrict__ gen_Wbih, const float* __restrict__ gen_bbih,
    const float* __restrict__ gen_Wbhh, const float* __restrict__ gen_bbhh,
    const float* __restrict__ base,
    float* __restrict__ WihAllT, float* __restrict__ WhhAllT,
    float* __restrict__ bihAll, float* __restrict__ bhhAll)
{
    __shared__ float Bs[64][132];
    __shared__ float Ws[16][132];
    __shared__ float bs[128];
    int rtile = blockIdx.x, ky = blockIdx.y, mat = blockIdx.z;
    int r0 = rtile * 128;
    bool normal = (ky < 128);
    int k = normal ? ky : 0;
    const float* W  = normal ? (mat ? gen_Whh : gen_Wih) : (mat ? gen_Wbhh : gen_Wbih);
    const float* bi = normal ? (mat ? gen_bhh : gen_bih) : (mat ? gen_bbhh : gen_bbih);
    float* out      = normal ? (mat ? WhhAllT : WihAllT) : (mat ? bhhAll : bihAll);
    int rowmul = normal ? 128 : 1;
    size_t ostride = normal ? (size_t)GENROWS : (size_t)R3sz;
    size_t obase   = normal ? (size_t)k * R3sz + r0 : (size_t)r0;

    int tid = threadIdx.x, tx = tid & 15, ty = tid >> 4;
#pragma unroll
    for (int l = 0; l < 8; l++) {
        int e = l * 256 + tid;
        int i = e >> 5, p4 = (e & 31) * 4;
        *(float4*)&Bs[i][p4] = *(const float4*)&base[(size_t)i * Rsz + p4];
    }
    if (tid < 128) bs[tid] = bi[(size_t)(r0 + tid) * rowmul + k];

    float acc[4][8];
#pragma unroll
    for (int i = 0; i < 4; i++)
#pragma unroll
        for (int j = 0; j < 8; j++) acc[i][j] = 0.f;

    for (int c = 0; c < 8; c++) {
        int p0 = c * 16;
#pragma unroll
        for (int l = 0; l < 2; l++) {
            int e = l * 256 + tid;
            int rr = e >> 2, pq = (e & 3) * 4;
            size_t rowidx = (size_t)(r0 + rr) * rowmul + k;
            float4 v = *(const float4*)&W[rowidx * Rsz + p0 + pq];
            Ws[pq + 0][rr] = v.x;
            Ws[pq + 1][rr] = v.y;
            Ws[pq + 2][rr] = v.z;
            Ws[pq + 3][rr] = v.w;
        }
        __syncthreads();
#pragma unroll
        for (int kk = 0; kk < 16; kk++) {
            float a[4], b8[8];
#pragma unroll
            for (int ii = 0; ii < 4; ii++) a[ii] = Bs[ty * 4 + ii][p0 + kk];
            *(float4*)&b8[0] = *(const float4*)&Ws[kk][tx * 4];
            *(float4*)&b8[4] = *(const float4*)&Ws[kk][64 + tx * 4];
#pragma unroll
            for (int ii = 0; ii < 4; ii++)
#pragma unroll
                for (int jj = 0; jj < 8; jj++)
                    acc[ii][jj] = fmaf(a[ii], b8[jj], acc[ii][jj]);
        }
        __syncthreads();
    }
#pragma unroll
    for (int ii = 0; ii < 4; ii++) {
        int i = ty * 4 + ii;
        float* op = out + (size_t)i * ostride + obase;
        *(float4*)&op[tx * 4] =
            make_float4(acc[ii][0] + bs[tx * 4 + 0], acc[ii][1] + bs[tx * 4 + 1],
                        acc[ii][2] + bs[tx * 4 + 2], acc[ii][3] + bs[tx * 4 + 3]);
        *(float4*)&op[64 + tx * 4] =
            make_float4(acc[ii][4] + bs[64 + tx * 4 + 0], acc[ii][5] + bs[64 + tx * 4 + 1],
                        acc[ii][6] + bs[64 + tx * 4 + 2], acc[ii][7] + bs[64 + tx * 4 + 3]);
    }
}

// =====================================================================
// Fused image-side precompute. grid 64.
// =====================================================================
__global__ __launch_bounds__(256) void img_kernel(
    const float* __restrict__ img_embed, const float* __restrict__ W_reduce_img,
    const float* __restrict__ b_reduce_img,
    float* __restrict__ base, float* __restrict__ iv)
{
    int i = blockIdx.x;
    int tid = threadIdx.x;
    __shared__ float row[Lsz];
    __shared__ float ps[4];
    for (int c = tid; c < Lsz; c += 256) {
        float s = 0.f;
        for (int r = 0; r < REG; r++) s += img_embed[((size_t)i * REG + r) * Lsz + c];
        row[c] = s * (1.f / (float)REG);
    }
    __syncthreads();
    float ss = 0.f;
    for (int c = tid; c < Lsz; c += 256) { float x = row[c]; ss = fmaf(x, x, ss); }
#pragma unroll
    for (int off = 32; off; off >>= 1) ss += __shfl_down(ss, off, 64);
    int lane = tid & 63, w = tid >> 6;
    if (lane == 0) ps[w] = ss;
    __syncthreads();
    float inv = 1.f / (sqrtf(ps[0] + ps[1] + ps[2] + ps[3]) + 1e-8f);
    for (int c = tid; c < Lsz; c += 256)
        iv[(size_t)i * Lsz + c] = row[c] * inv;
    for (int o = w * 32; o < w * 32 + 32; o++) {
        float a = 0.f;
        const float* wr = W_reduce_img + (size_t)o * Lsz + lane * 16;
        const float* rr = row + lane * 16;
#pragma unroll
        for (int u = 0; u < 16; u++) a = fmaf(wr[u], rr[u], a);
#pragma unroll
        for (int off = 32; off; off >>= 1) a += __shfl_down(a, off, 64);
        if (lane == 0) base[(size_t)i * Rsz + o] = a + b_reduce_img[o];
    }
}

// =====================================================================
// Pack gru_Whh_{f,b} [3072][1024] into MFMA A-frags, bf16 hi/lo.
// WFh/WFl: [dir][mstrip 192][k0 32][lane 64][elem 8]. grid (8,192,2).
// =====================================================================
__global__ __launch_bounds__(256) void packwhh_kernel(
    const float* __restrict__ Wf, const float* __restrict__ Wb,
    float* __restrict__ WFh_, float* __restrict__ WFl_)
{
    int tid = threadIdx.x;
    int l = tid & 63, wid = tid >> 6;
    int k0 = blockIdx.x * 4 + wid;
    int mstrip = blockIdx.y;
    int dir = blockIdx.z;
    const float* W = dir ? Wb : Wf;
    int row = mstrip * 16 + (l & 15);
    int col = k0 * 32 + (l >> 4) * 8;
    float v[8];
    *(float4*)&v[0] = *(const float4*)&W[(size_t)row * Lsz + col];
    *(float4*)&v[4] = *(const float4*)&W[(size_t)row * Lsz + col + 4];
    size_t off = ((size_t)(dir * 192 + mstrip) * 32 + k0) * 512 + l * 8;
    pack8(v, (ushort*)WFh_ + off, (ushort*)WFl_ + off);
}

// =====================================================================
// Pack WihAllT/WhhAllT [i][k 128][row 384] into per-image A-frags.
// GF: [i][mat][mstrip 24][kt 4][lane 64][elem 8]. grid (24,2,64).
// =====================================================================
__global__ __launch_bounds__(256) void packgenw_kernel(
    const float* __restrict__ WihAllT, const float* __restrict__ WhhAllT,
    float* __restrict__ GFh_, float* __restrict__ GFl_)
{
    int tid = threadIdx.x;
    int l = tid & 63, kt = tid >> 6;
    int mstrip = blockIdx.x;
    int mat = blockIdx.y;
    int i = blockIdx.z;
    const float* W = (mat ? WhhAllT : WihAllT) + (size_t)i * GENROWS;
    int row = mstrip * 16 + (l & 15);
    int kb = kt * 32 + (l >> 4) * 8;
    float v[8];
#pragma unroll
    for (int e = 0; e < 8; e++)
        v[e] = W[(size_t)(kb + e) * R3sz + row];
    size_t off = (((size_t)(i * 2 + mat) * 24 + mstrip) * 4 + kt) * 512 + l * 8;
    pack8(v, (ushort*)GFh_ + off, (ushort*)GFl_ + off);
}

// =====================================================================
// Pack capT2 [128][2048] into B-frags: [kt 4][ct' 128][lane 64][elem 8].
// grid (128). wave = kt.
// =====================================================================
__global__ __launch_bounds__(256) void packcap_kernel(
    const float* __restrict__ capT2, float* __restrict__ CFh_, float* __restrict__ CFl_)
{
    int tid = threadIdx.x;
    int l = tid & 63, kt = tid >> 6;
    int ctp = blockIdx.x;
    int col = ctp * 16 + (l & 15);
    int kb = kt * 32 + (l >> 4) * 8;
    float v[8];
#pragma unroll
    for (int e = 0; e < 8; e++)
        v[e] = capT2[(size_t)(kb + e) * NC + col];
    size_t off = ((size_t)kt * 128 + ctp) * 512 + l * 8;
    pack8(v, (ushort*)CFh_ + off, (ushort*)CFl_ + off);
}

// =====================================================================
// Pack gru_Wih_{f,b} [3072][300] into A-frags, K padded to 320.
// WihF: [dir][mstrip 192][kt 10][lane 64][elem 8]. grid (3,192,2).
// =====================================================================
__global__ __launch_bounds__(256) void packwih_kernel(
    const float* __restrict__ Wf, const float* __restrict__ Wb,
    float* __restrict__ Fh, float* __restrict__ Fl)
{
    int tid = threadIdx.x, l = tid & 63, wid = tid >> 6;
    int kt = blockIdx.x * 4 + wid;
    int m = blockIdx.y, dir = blockIdx.z;
    if (kt >= 10) return;
    const float* W = dir ? Wb : Wf;
    int row = m * 16 + (l & 15);
    int kb = kt * 32 + (l >> 4) * 8;
    float v[8];
#pragma unroll
    for (int e = 0; e < 8; e++) {
        int k = kb + e;
        v[e] = (k < DIN) ? W[(size_t)row * DIN + k] : 0.f;
    }
    size_t off = (((size_t)dir * 192 + m) * 10 + kt) * 512 + l * 8;
    pack8(v, (ushort*)Fh + off, (ushort*)Fl + off);
}

// =====================================================================
// Pack cap_embed [b][t][300] into B-frags [kt 10][ct 128][lane][8].
// grid (128, 3).
// =====================================================================
__global__ __launch_bounds__(256) void packcapb_kernel(
    const float* __restrict__ cap_embed, float* __restrict__ Fh, float* __restrict__ Fl)
{
    int tid = threadIdx.x, l = tid & 63, wid = tid >> 6;
    int ct = blockIdx.x;
    int kt = blockIdx.y * 4 + wid;
    if (kt >= 10) return;
    int c = ct * 16 + (l & 15), t = c >> 6, b = c & 63;
    int kb = kt * 32 + (l >> 4) * 8;
    float v[8];
#pragma unroll
    for (int e = 0; e < 8; e++) {
        int k = kb + e;
        v[e] = (k < DIN) ? cap_embed[((size_t)b * Tsz + t) * DIN + k] : 0.f;
    }
    size_t off = ((size_t)kt * 128 + ct) * 512 + l * 8;
    pack8(v, (ushort*)Fh + off, (ushort*)Fl + off);
}

// =====================================================================
// Generic A-frag pack from ROW-MAJOR W [N][lda] (k window at koff).
// Frags: [strip][NKT][lane 64][elem 8]. grid (nstrips, ceil(NKT/4)).
// =====================================================================
__global__ __launch_bounds__(256) void packA_rm(
    const float* __restrict__ W, float* __restrict__ Fh, float* __restrict__ Fl,
    int lda, int koff, int NKT)
{
    int tid = threadIdx.x, l = tid & 63, wid = tid >> 6;
    int strip = blockIdx.x;
    int kt = blockIdx.y * 4 + wid;
    if (kt >= NKT) return;
    int row = strip * 16 + (l & 15);
    int kb = kt * 32 + (l >> 4) * 8;
    float v[8];
    *(float4*)&v[0] = *(const float4*)&W[(size_t)row * lda + koff + kb];
    *(float4*)&v[4] = *(const float4*)&W[(size_t)row * lda + koff + kb + 4];
    size_t off = ((size_t)strip * NKT + kt) * 512 + l * 8;
    pack8(v, (ushort*)Fh + off, (ushort*)Fl + off);
}

// =====================================================================
// Generic B-frag pack from X [K][ncols] (column layout). Frags:
// [kt][ct][lane 64][elem 8]. grid (ncols/16, ceil(NKT/4)).
// =====================================================================
__global__ __launch_bounds__(256) void packB_kernel(
    const float* __restrict__ X, float* __restrict__ Fh, float* __restrict__ Fl,
    int ncols, int NKT)
{
    int tid = threadIdx.x, l = tid & 63, wid = tid >> 6;
    int ctp = blockIdx.x;
    int kt = blockIdx.y * 4 + wid;
    if (kt >= NKT) return;
    int col = ctp * 16 + (l & 15);
    int kb = kt * 32 + (l >> 4) * 8;
    float v[8];
#pragma unroll
    for (int e = 0; e < 8; e++)
        v[e] = X[(size_t)(kb + e) * ncols + col];
    size_t off = ((size_t)kt * (ncols >> 4) + ctp) * 512 + l * 8;
    pack8(v, (ushort*)Fh + off, (ushort*)Fl + off);
}

// =====================================================================
// Generic MFMA bf16x3 TT GEMM: C[n][c] = sum_k W[n][k] X[k][c] (+bias).
// A-frags [strip][NKT][512], B-frags [kt][nct][512].
// Block: 4 waves x (2 mstrips, 8 ctiles); grid (ncols/128, N/128).
// =====================================================================
__global__ __launch_bounds__(256) void gemm_mfma(
    const float* __restrict__ AFh, const float* __restrict__ AFl,
    const float* __restrict__ BFh, const float* __restrict__ BFl,
    const float* __restrict__ bias, float* __restrict__ C,
    int NKT, int ncols)
{
    __shared__ __align__(16) ushort BsH[8][512];
    __shared__ __align__(16) ushort BsL[8][512];
    int tid = threadIdx.x, l = tid & 63, wid = tid >> 6;
    int ctg = blockIdx.x, mg = blockIdx.y;
    int ct0 = ctg * 8;
    int m0 = mg * 8 + wid * 2;
    int nct = ncols >> 4;
    const ushort* AH = (const ushort*)AFh;
    const ushort* AL = (const ushort*)AFl;
    const ushort* BH = (const ushort*)BFh;
    const ushort* BL = (const ushort*)BFl;

    f32x4 acc[2][8];
#pragma unroll
    for (int m = 0; m < 2; m++)
#pragma unroll
        for (int ct = 0; ct < 8; ct++) acc[m][ct] = (f32x4){0.f, 0.f, 0.f, 0.f};

    for (int kt = 0; kt < NKT; kt++) {
        __syncthreads();
#pragma unroll
        for (int u = 0; u < 2; u++) {
            int e = u * 256 + tid;       // e < 512
            int ct = e >> 6, p8 = (e & 63) * 8;
            *(uint4*)&BsH[ct][p8] = *(const uint4*)&BH[((size_t)kt * nct + ct0 + ct) * 512 + p8];
            *(uint4*)&BsL[ct][p8] = *(const uint4*)&BL[((size_t)kt * nct + ct0 + ct) * 512 + p8];
        }
        __syncthreads();
        bf16x8 Ah[2], Al[2];
#pragma unroll
        for (int m = 0; m < 2; m++) {
            size_t ao = ((size_t)(m0 + m) * NKT + kt) * 512 + l * 8;
            Ah[m] = *(const bf16x8*)(AH + ao);
            Al[m] = *(const bf16x8*)(AL + ao);
        }
#pragma unroll
        for (int ct = 0; ct < 8; ct++) {
            bf16x8 Bh = *(const bf16x8*)&BsH[ct][l * 8];
            bf16x8 Bl = *(const bf16x8*)&BsL[ct][l * 8];
#pragma unroll
            for (int m = 0; m < 2; m++) {
                acc[m][ct] = __builtin_amdgcn_mfma_f32_16x16x32_bf16(Ah[m], Bh, acc[m][ct], 0, 0, 0);
                acc[m][ct] = __builtin_amdgcn_mfma_f32_16x16x32_bf16(Ah[m], Bl, acc[m][ct], 0, 0, 0);
                acc[m][ct] = __builtin_amdgcn_mfma_f32_16x16x32_bf16(Al[m], Bh, acc[m][ct], 0, 0, 0);
            }
        }
    }
    int row4 = (l >> 4) * 4, col = l & 15;
#pragma unroll
    for (int m = 0; m < 2; m++) {
        int nb_ = (m0 + m) * 16 + row4;
#pragma unroll
        for (int r = 0; r < 4; r++) {
            float bv = bias ? bias[nb_ + r] : 0.f;
#pragma unroll
            for (int ct = 0; ct < 8; ct++)
                C[(size_t)(nb_ + r) * ncols + (size_t)(ct0 + ct) * 16 + col] = acc[m][ct][r] + bv;
        }
    }
}

// =====================================================================
// Recurrence step (MFMA bf16x3 GEMM + in-block reduce + gates).
// Launched once per step. grid 384 x 256thr:
//  bid<128: cap GRU. dir = bid>>6, j-strip js = bid&63 (16 h-dims).
//  bid>=128: gen GRU. i = (bid-128)>>2, strip-pair p = (bid-128)&3.
// =====================================================================
__global__ __launch_bounds__(256) void rec_kernel(
    const float* __restrict__ WhhF_h, const float* __restrict__ WhhF_l,
    const float* __restrict__ WgenF_h, const float* __restrict__ WgenF_l,
    const float* __restrict__ capF_h, const float* __restrict__ capF_l,
    float* capHF_h, float* capHF_l,
    float* genHF_h, float* genHF_l,
    const float* __restrict__ giT2_f, const float* __restrict__ giT2_b,
    float* hfT, float* hbT,
    const float* __restrict__ bhh_f, const float* __restrict__ bhh_b,
    const float* __restrict__ bihAll, const float* __restrict__ bhhAll,
    float* hA, float* hB, float* hmaxT,
    int s)
{
    __shared__ float red[48 * 256];
    int tid = threadIdx.x, l = tid & 63, wid = tid >> 6;
    int bid = blockIdx.x;
    int ping = (s & 1) ^ 1;   // read-side h-frag buffer
    int pong = s & 1;         // write-side

    if (bid < 128) {
        // ---------------- cap GRU ----------------
        int dir = bid >> 6, js = bid & 63;
        f32x4 acc[3][4];
#pragma unroll
        for (int g = 0; g < 3; g++)
#pragma unroll
            for (int ct = 0; ct < 4; ct++) acc[g][ct] = (f32x4){0.f, 0.f, 0.f, 0.f};

        if (s > 0) {
            const ushort* Wh = (const ushort*)WhhF_h + (size_t)dir * (192 * 32 * 512);
            const ushort* Wl = (const ushort*)WhhF_l + (size_t)dir * (192 * 32 * 512);
            const ushort* Hh = (const ushort*)capHF_h + (size_t)(dir * 2 + ping) * 65536;
            const ushort* Hl = (const ushort*)capHF_l + (size_t)(dir * 2 + ping) * 65536;
            for (int k8 = 0; k8 < 8; k8++) {
                int k0 = wid * 8 + k8;
                bf16x8 Bh[4], Bl[4], Ah[3], Al[3];
#pragma unroll
                for (int ct = 0; ct < 4; ct++) {
                    size_t fo = ((size_t)k0 * 4 + ct) * 512 + l * 8;
                    Bh[ct] = *(const bf16x8*)(Hh + fo);
                    Bl[ct] = *(const bf16x8*)(Hl + fo);
                }
#pragma unroll
                for (int g = 0; g < 3; g++) {
                    size_t fo = ((size_t)(g * 64 + js) * 32 + k0) * 512 + l * 8;
                    Ah[g] = *(const bf16x8*)(Wh + fo);
                    Al[g] = *(const bf16x8*)(Wl + fo);
                }
#pragma unroll
                for (int g = 0; g < 3; g++)
#pragma unroll
                    for (int ct = 0; ct < 4; ct++)
                        acc[g][ct] = __builtin_amdgcn_mfma_f32_16x16x32_bf16(
                            Ah[g], Bh[ct], acc[g][ct], 0, 0, 0);
#pragma unroll
                for (int g = 0; g < 3; g++)
#pragma unroll
                    for (int ct = 0; ct < 4; ct++)
                        acc[g][ct] = __builtin_amdgcn_mfma_f32_16x16x32_bf16(
                            Ah[g], Bl[ct], acc[g][ct], 0, 0, 0);
#pragma unroll
                for (int g = 0; g < 3; g++)
#pragma unroll
                    for (int ct = 0; ct < 4; ct++)
                        acc[g][ct] = __builtin_amdgcn_mfma_f32_16x16x32_bf16(
                            Al[g], Bh[ct], acc[g][ct], 0, 0, 0);
            }
        }
#pragma unroll
        for (int g = 0; g < 3; g++)
#pragma unroll
            for (int ct = 0; ct < 4; ct++)
                *(f32x4*)&red[((wid * 3 + g) * 4 + ct) * 256 + l * 4] = acc[g][ct];
        __syncthreads();

        const float* giT = dir ? giT2_b : giT2_f;
        float* hT        = dir ? hbT   : hfT;
        const float* bhh = dir ? bhh_b : bhh_f;
        int t  = dir ? (Tsz - 1 - s) : s;
        int tp = dir ? (t + 1) : (t - 1);
        ushort* Ch = (ushort*)capHF_h + (size_t)(dir * 2 + pong) * 65536;
        ushort* Cl = (ushort*)capHF_l + (size_t)(dir * 2 + pong) * 65536;
#pragma unroll
        for (int u = 0; u < 4; u++) {
            int e = u * 256 + tid;
            int jj = e >> 6, b = e & 63;
            int j = js * 16 + jj;
            float gh[3] = {0.f, 0.f, 0.f};
            if (s > 0) {
                int lane_ = ((jj >> 2) << 4) | (b & 15);
                int reg = jj & 3, ct = b >> 4;
#pragma unroll
                for (int w = 0; w < 4; w++)
#pragma unroll
                    for (int g = 0; g < 3; g++)
                        gh[g] += red[((w * 3 + g) * 4 + ct) * 256 + lane_ * 4 + reg];
            }
            size_t gc = (size_t)t * 64 + b;
            float gr = giT[(size_t)j * NC + gc];
            float gz = giT[((size_t)Lsz + j) * NC + gc];
            float gn = giT[((size_t)2 * Lsz + j) * NC + gc];
            float hp = (s > 0) ? hT[((size_t)tp * Lsz + j) * Bsz + b] : 0.f;
            float r = sigf(gr + gh[0] + bhh[j]);
            float z = sigf(gz + gh[1] + bhh[Lsz + j]);
            float n = tanhf(gn + r * (gh[2] + bhh[2 * Lsz + j]));
            float h = (1.f - z) * n + z * hp;
            hT[((size_t)t * Lsz + j) * Bsz + b] = h;
            size_t fo = hfrag_off(j, b);
            ushort hb = f2bf(h);
            Ch[fo] = hb;
            Cl[fo] = f2bf(h - bf2f(hb));
        }
    } else {
        // ---------------- gen GRU ----------------
        int g2 = bid - 128;
        int i = g2 >> 2;
        int p = g2 & 3;
        int mat = wid & 1;    // 0 = ih, 1 = hh
        int sl = wid >> 1;    // strip within pair
        int strip = p * 2 + sl;
        float* hcurT = (s & 1) ? hB : hA;
        const float* hprevT = (s & 1) ? hA : hB;
        f32x4 acc[3][4];
#pragma unroll
        for (int g = 0; g < 3; g++)
#pragma unroll
            for (int ct = 0; ct < 4; ct++) acc[g][ct] = (f32x4){0.f, 0.f, 0.f, 0.f};

        if (mat == 0 || s > 0) {
            const ushort* Ahp = (const ushort*)WgenF_h + (size_t)(i * 2 + mat) * 96 * 512;
            const ushort* Alp = (const ushort*)WgenF_l + (size_t)(i * 2 + mat) * 96 * 512;
            const ushort* Bhp;
            const ushort* Blp;
            if (mat == 0) {
                Bhp = (const ushort*)capF_h;
                Blp = (const ushort*)capF_l;
            } else {
                Bhp = (const ushort*)genHF_h + (size_t)(ping * 64 + i) * 8192;
                Blp = (const ushort*)genHF_l + (size_t)(ping * 64 + i) * 8192;
            }
            for (int kt = 0; kt < 4; kt++) {
                bf16x8 Bh[4], Bl[4], Ah[3], Al[3];
#pragma unroll
                for (int ct = 0; ct < 4; ct++) {
                    size_t fo = (mat == 0)
                        ? ((size_t)kt * 128 + s * 4 + ct) * 512 + l * 8
                        : ((size_t)kt * 4 + ct) * 512 + l * 8;
                    Bh[ct] = *(const bf16x8*)(Bhp + fo);
                    Bl[ct] = *(const bf16x8*)(Blp + fo);
                }
#pragma unroll
                for (int g = 0; g < 3; g++) {
                    size_t fo = ((size_t)(g * 8 + strip) * 4 + kt) * 512 + l * 8;
                    Ah[g] = *(const bf16x8*)(Ahp + fo);
                    Al[g] = *(const bf16x8*)(Alp + fo);
                }
#pragma unroll
                for (int g = 0; g < 3; g++)
#pragma unroll
                    for (int ct = 0; ct < 4; ct++)
                        acc[g][ct] = __builtin_amdgcn_mfma_f32_16x16x32_bf16(
                            Ah[g], Bh[ct], acc[g][ct], 0, 0, 0);
#pragma unroll
                for (int g = 0; g < 3; g++)
#pragma unroll
                    for (int ct = 0; ct < 4; ct++)
                        acc[g][ct] = __builtin_amdgcn_mfma_f32_16x16x32_bf16(
                            Ah[g], Bl[ct], acc[g][ct], 0, 0, 0);
#pragma unroll
                for (int g = 0; g < 3; g++)
#pragma unroll
                    for (int ct = 0; ct < 4; ct++)
                        acc[g][ct] = __builtin_amdgcn_mfma_f32_16x16x32_bf16(
                            Al[g], Bh[ct], acc[g][ct], 0, 0, 0);
            }
        }
#pragma unroll
        for (int g = 0; g < 3; g++)
#pragma unroll
            for (int ct = 0; ct < 4; ct++)
                *(f32x4*)&red[(((sl * 2 + mat) * 3 + g) * 4 + ct) * 256 + l * 4] = acc[g][ct];
        __syncthreads();

        const float* bih = bihAll + (size_t)i * R3sz;
        const float* bhh = bhhAll + (size_t)i * R3sz;
        ushort* Gh = (ushort*)genHF_h + (size_t)(pong * 64 + i) * 8192;
        ushort* Gl = (ushort*)genHF_l + (size_t)(pong * 64 + i) * 8192;
#pragma unroll
        for (int u = 0; u < 8; u++) {
            int e = u * 256 + tid;
            int sl2 = e >> 10;
            int jj = (e >> 6) & 15;
            int b = e & 63;
            int j = (p * 2 + sl2) * 16 + jj;
            int lane_ = ((jj >> 2) << 4) | (b & 15);
            int reg = jj & 3, ct = b >> 4;
            float sih[3], shh[3];
#pragma unroll
            for (int g = 0; g < 3; g++) {
                sih[g] = red[(((sl2 * 2 + 0) * 3 + g) * 4 + ct) * 256 + lane_ * 4 + reg];
                shh[g] = (s > 0)
                    ? red[(((sl2 * 2 + 1) * 3 + g) * 4 + ct) * 256 + lane_ * 4 + reg]
                    : 0.f;
            }
            float r = sigf(sih[0] + bih[j] + shh[0] + bhh[j]);
            float z = sigf(sih[1] + bih[Rsz + j] + shh[1] + bhh[Rsz + j]);
            float n = tanhf(sih[2] + bih[2 * Rsz + j] + r * (shh[2] + bhh[2 * Rsz + j]));
            float hp = (s > 0) ? hprevT[((size_t)i * Rsz + j) * Bsz + b] : 0.f;
            float h = (1.f - z) * n + z * hp;
            size_t idx = ((size_t)i * Rsz + j) * Bsz + b;
            hcurT[idx] = h;
            hmaxT[idx] = (s == 0) ? h : fmaxf(hmaxT[idx], h);
            size_t fo = hfrag_off(j, b);
            ushort hb = f2bf(h);
            Gh[fo] = hb;
            Gl[fo] = f2bf(h - bf2f(hb));
        }
    }
}

// =====================================================================
// txt = (hf+hb)/2 -> row-major txt [b][t][c] AND column txtT [c][t*64+b].
// =====================================================================
__global__ __launch_bounds__(256) void txt_combine(
    const float* __restrict__ hfT, const float* __restrict__ hbT,
    float* __restrict__ txt, float* __restrict__ txtT)
{
    __shared__ float s[64][65];
    int t = blockIdx.x;
    int c0 = blockIdx.y * 64;
    int tid = threadIdx.x;
#pragma unroll
    for (int l = 0; l < 16; l++) {
        int e = l * 256 + tid;
        int cc = e >> 6, b = e & 63;
        size_t idx = ((size_t)t * Lsz + c0 + cc) * Bsz + b;
        s[cc][b] = 0.5f * (hfT[idx] + hbT[idx]);
    }
    __syncthreads();
#pragma unroll
    for (int l = 0; l < 16; l++) {
        int e = l * 256 + tid;
        int b = e >> 6, cc = e & 63;
        txt[((size_t)b * Tsz + t) * Lsz + c0 + cc] = s[cc][b];
    }
#pragma unroll
    for (int l = 0; l < 16; l++) {
        int e = l * 256 + tid;
        int cc = e >> 6, b = e & 63;
        txtT[(size_t)(c0 + cc) * NC + t * 64 + b] = s[cc][b];
    }
}

// =====================================================================
// Self-attention. v read from vbuf [c][t*64+b] (bias pre-added).
// =====================================================================
__global__ __launch_bounds__(256) void attn_kernel(
    const float* __restrict__ q, const float* __restrict__ kmat,
    const float* __restrict__ vbuf,
    const float* __restrict__ txt,
    const float* __restrict__ gamma_p, float* __restrict__ xattn)
{
    __shared__ float qs[32][129];
    __shared__ float ks[32][129];
    __shared__ float Sc[32][33];
    __shared__ float vs[128][33];
    int b = blockIdx.x;
    int c0 = blockIdx.y * 128;
    int tid = threadIdx.x;
    for (int e = tid; e < Tsz * Rsz; e += 256) {
        qs[e >> 7][e & 127] = q[(size_t)b * Tsz * Rsz + e];
        ks[e >> 7][e & 127] = kmat[(size_t)b * Tsz * Rsz + e];
    }
    for (int e = tid; e < 128 * 32; e += 256) {
        int cc = e >> 5, ss = e & 31;
        vs[cc][ss] = vbuf[(size_t)(c0 + cc) * NC + ss * 64 + b];
    }
    __syncthreads();
    for (int e = tid; e < Tsz * Tsz; e += 256) {
        int t = e >> 5, ss = e & 31;
        float acc = 0.f;
#pragma unroll 4
        for (int o = 0; o < Rsz; o++) acc = fmaf(qs[t][o], ks[ss][o], acc);
        Sc[t][ss] = acc;
    }
    __syncthreads();
    if (tid < 32) {
        int t = tid;
        float mx = -1e30f;
#pragma unroll
        for (int ss = 0; ss < 32; ss++) mx = fmaxf(mx, Sc[t][ss]);
        float sum = 0.f;
        float ex[32];
#pragma unroll
        for (int ss = 0; ss < 32; ss++) { ex[ss] = __expf(Sc[t][ss] - mx); sum += ex[ss]; }
        float inv = 1.f / sum;
#pragma unroll
        for (int ss = 0; ss < 32; ss++) Sc[t][ss] = ex[ss] * inv;
    }
    __syncthreads();
    float gamma = *gamma_p;
    for (int e = tid; e < Tsz * 128; e += 256) {
        int tt = e >> 7, cc = e & 127;
        float acc = 0.f;
#pragma unroll 8
        for (int ss = 0; ss < Tsz; ss++)
            acc = fmaf(Sc[tt][ss], vs[cc][ss], acc);
        size_t oidx = ((size_t)b * Tsz + tt) * Lsz + c0 + cc;
        xattn[oidx] = gamma * acc + txt[oidx];
    }
}

// ---------------- length-masked mean pool, grid (64,4) ----------------
__global__ __launch_bounds__(256) void pool_kernel(
    const float* __restrict__ xattn, const int* __restrict__ lens,
    float* __restrict__ txt_embed)
{
    int b = blockIdx.x;
    int c = blockIdx.y * 256 + threadIdx.x;
    int len = lens[b];
    float s = 0.f;
    for (int t = 0; t < len; t++) s += xattn[((size_t)b * Tsz + t) * Lsz + c];
    txt_embed[(size_t)b * Lsz + c] = s / (float)len;
}

// =====================================================================
// base_fcT[n][b] = dot(txt_emb[b][:], W_txt_fc[n][0:1024]). grid 256.
// =====================================================================
__global__ __launch_bounds__(256) void basefc_kernel(
    const float* __restrict__ temb, const float* __restrict__ W,
    float* __restrict__ outT)
{
    int lane = threadIdx.x & 63, w = threadIdx.x >> 6;
    int n = blockIdx.x * 4 + w;
    const float* wr = W + (size_t)n * (Rsz + Lsz) + lane * 16;
    float wv[16];
#pragma unroll
    for (int u = 0; u < 4; u++) *(float4*)&wv[u * 4] = *(const float4*)&wr[u * 4];
    for (int b = 0; b < Bsz; b++) {
        const float* te = temb + (size_t)b * Lsz + lane * 16;
        float tv[16];
#pragma unroll
        for (int u = 0; u < 4; u++) *(float4*)&tv[u * 4] = *(const float4*)&te[u * 4];
        float a = 0.f;
#pragma unroll
        for (int u = 0; u < 16; u++) a = fmaf(wv[u], tv[u], a);
#pragma unroll
        for (int off = 32; off; off >>= 1) a += __shfl_down(a, off, 64);
        if (lane == 0) outT[(size_t)n * Bsz + b] = a;
    }
}

// ---- hmaxT [i][j][b] -> hstdT [j][i*64+b], coalesced permute. grid 64 ----
__global__ __launch_bounds__(256) void hstdT_kernel(
    const float* __restrict__ hmaxT, float* __restrict__ hstdT)
{
    int i = blockIdx.x, tid = threadIdx.x;
    int b = tid & 63, j0 = tid >> 6;
#pragma unroll
    for (int l = 0; l < 32; l++) {
        int j = l * 4 + j0;
        hstdT[(size_t)j * 4096 + i * 64 + b] = hmaxT[((size_t)i * Rsz + j) * Bsz + b];
    }
}

// =====================================================================
// sims partial reduce: column layouts, fully coalesced. grid (64, 4).
// =====================================================================
__global__ __launch_bounds__(256) void sims_part(
    const float* __restrict__ fcT, const float* __restrict__ base_fcT,
    const float* __restrict__ bfc, const float* __restrict__ iv,
    float* __restrict__ accA, float* __restrict__ accB)
{
    int i = blockIdx.x, cs = blockIdx.y;
    int tid = threadIdx.x;
    int w = tid >> 6, b = tid & 63;
    float s1 = 0.f, s2 = 0.f;
    for (int u = 0; u < 64; u++) {
        int c = cs * 256 + w * 64 + u;
        float f = fcT[(size_t)c * 4096 + i * 64 + b] + base_fcT[(size_t)c * Bsz + b] + bfc[c];
        s1 = fmaf(f, f, s1);
        s2 = fmaf(f, iv[(size_t)i * Lsz + c], s2);
    }
    int m = i * 64 + b;
    atomicAdd(&accA[m], s1);
    atomicAdd(&accB[m], s2);
}

__global__ __launch_bounds__(256) void sims_final(
    const float* __restrict__ accA, const float* __restrict__ accB,
    float* __restrict__ out)
{
    int m = blockIdx.x * 256 + threadIdx.x;
    out[m] = accB[m] / (sqrtf(accA[m]) + 1e-8f);
}

// =====================================================================
extern "C" void kernel_launch(void* const* d_in, const int* in_sizes, int n_in,
                              void* d_out, int out_size, void* d_ws, size_t ws_size,
                              hipStream_t stream)
{
    const float* img_embed    = (const float*)d_in[0];
    const float* cap_embed    = (const float*)d_in[1];
    const int*   lens         = (const int*)d_in[2];
    const float* W_reduce_img = (const float*)d_in[3];
    const float* b_reduce_img = (const float*)d_in[4];
    const float* W_reduce_txt = (const float*)d_in[5];
    const float* b_reduce_txt = (const float*)d_in[6];
    const float* gru_Wih_f    = (const float*)d_in[7];
    const float* gru_Whh_f    = (const float*)d_in[8];
    const float* gru_bih_f    = (const float*)d_in[9];
    const float* gru_bhh_f    = (const float*)d_in[10];
    const float* gru_Wih_b    = (const float*)d_in[11];
    const float* gru_Whh_b    = (const float*)d_in[12];
    const float* gru_bih_b    = (const float*)d_in[13];
    const float* gru_bhh_b    = (const float*)d_in[14];
    const float* sa_Wq        = (const float*)d_in[15];
    const float* sa_bq        = (const float*)d_in[16];
    const float* sa_Wk        = (const float*)d_in[17];
    const float* sa_bk        = (const float*)d_in[18];
    const float* sa_Wv        = (const float*)d_in[19];
    const float* sa_bv        = (const float*)d_in[20];
    const float* sa_gamma     = (const float*)d_in[21];
    const float* gen_Wih      = (const float*)d_in[22];
    const float* gen_bih      = (const float*)d_in[23];
    const float* gen_Whh      = (const float*)d_in[24];
    const float* gen_bhh      = (const float*)d_in[25];
    const float* gen_Wbih     = (const float*)d_in[26];
    const float* gen_bbih     = (const float*)d_in[27];
    const float* gen_Wbhh     = (const float*)d_in[28];
    const float* gen_bbhh     = (const float*)d_in[29];
    const float* W_txt_fc     = (const float*)d_in[30];
    const float* b_txt_fc     = (const float*)d_in[31];

    float* ws = (float*)d_ws;
    size_t off = 0;
    auto alloc = [&](size_t n) { float* p = ws + off; off += n; return p; };
    float* giT2_f   = alloc((size_t)H3sz * NC);
    float* giT2_b   = alloc((size_t)H3sz * NC);
    float* hfT      = alloc((size_t)Tsz * Lsz * Bsz);
    float* hbT      = alloc((size_t)Tsz * Lsz * Bsz);
    float* capTr    = alloc((size_t)KPAD * NC);
    float* capT2    = alloc((size_t)Rsz * NC);
    float* txt      = alloc((size_t)Bsz * Tsz * Lsz);
    float* txtT     = alloc((size_t)Lsz * NC);
    float* qbuf     = alloc((size_t)Bsz * Tsz * Rsz);
    float* kbuf     = alloc((size_t)Bsz * Tsz * Rsz);
    // Big pool: during the loop it holds the bf16 hi/lo rec-weight frags;
    // after the loop the attention/fc buffers reuse it (disjoint lifetimes).
    float* pool     = alloc((size_t)12582912);
    float* WhhFh  = pool;                  // 3,145,728 floats each
    float* WhhFl  = pool + 3145728;
    float* WgenFh = pool + 6291456;
    float* WgenFl = pool + 9437184;
    // post-loop overlay of the same pool:
    float* txtFh  = pool;                  // 1,048,576
    float* txtFl  = pool + 1048576;        // 1,048,576
    float* hstdFh = pool + 2097152;        //   262,144
    float* hstdFl = pool + 2359296;        //   262,144
    float* vbuf   = pool + 2621440;        // 2,097,152
    float* qkbuf  = pool + 4718592;        //   524,288
    float* fcT    = pool + 5242880;        // 4,194,304  (ends 9,437,184)
    float* xattn    = alloc((size_t)Bsz * Tsz * Lsz);
    float* txt_emb  = alloc((size_t)Bsz * Lsz);
    float* base     = alloc((size_t)Bsz * Rsz);
    float* iv       = alloc((size_t)Bsz * Lsz);
    float* WihAllT  = alloc((size_t)Bsz * GENROWS);
    float* WhhAllT  = alloc((size_t)Bsz * GENROWS);
    float* WihFh    = alloc((size_t)983040);   // Wih A-frags hi (bf16, K=320)
    float* WihFl    = alloc((size_t)983040);
    float* capBFh   = alloc((size_t)327680);   // cap_embed B-frags hi
    float* capBFl   = alloc((size_t)327680);
    float* WvFh     = alloc((size_t)524288);   // sa_Wv A-frags (64 strips x 32 kt)
    float* WvFl     = alloc((size_t)524288);
    float* WqkFh    = alloc((size_t)131072);   // sa_Wq+sa_Wk A-frags (16 strips x 32 kt)
    float* WqkFl    = alloc((size_t)131072);
    float* WfcFh    = alloc((size_t)65536);    // W_txt_fc[:,1024:] A-frags (64 x 4)
    float* WfcFl    = alloc((size_t)65536);
    float* WrtT     = alloc((size_t)KPAD * Rsz);
    float* bihAll   = alloc((size_t)Bsz * R3sz);
    float* bhhAll   = alloc((size_t)Bsz * R3sz);
    float* hA       = alloc((size_t)Bsz * Rsz * Bsz);
    float* hB       = alloc((size_t)Bsz * Rsz * Bsz);
    float* hmaxT    = alloc((size_t)Bsz * Rsz * Bsz);
    float* hstdT    = alloc((size_t)Rsz * Bsz * Bsz);
    float* base_fcT = alloc((size_t)Lsz * Bsz);
    float* accA     = alloc(4096);
    float* accB     = alloc(4096);
    float* capFh    = alloc(131072);   // capT2 B-frags hi (bf16)
    float* capFl    = alloc(131072);
    float* capHFh   = alloc(131072);   // cap h B-frags [dir][ping]
    float* capHFl   = alloc(131072);
    float* genHFh   = alloc(524288);   // gen h B-frags [ping][i]
    float* genHFl   = alloc(524288);

    // 0) zero the sims accumulators
    hipMemsetAsync(accA, 0, 2 * 4096 * sizeof(float), stream);

    // 1) one-time transposes / packs (A-frags read row-major weights directly)
    transp_kernel<<<dim3(5, 2), 256, 0, stream>>>(W_reduce_txt, WrtT, Rsz, DIN, KPAD, DIN, 0);
    captr_kernel<<<dim3(32, 5), 256, 0, stream>>>(cap_embed, capTr);
    packwih_kernel<<<dim3(3, 192, 2), 256, 0, stream>>>(gru_Wih_f, gru_Wih_b, WihFh, WihFl);
    packcapb_kernel<<<dim3(128, 3), 256, 0, stream>>>(cap_embed, capBFh, capBFl);
    packA_rm<<<dim3(64, 8), 256, 0, stream>>>(sa_Wv, WvFh, WvFl, Lsz, 0, 32);
    packA_rm<<<dim3(8, 8), 256, 0, stream>>>(sa_Wq, WqkFh, WqkFl, Lsz, 0, 32);
    packA_rm<<<dim3(8, 8), 256, 0, stream>>>(sa_Wk, WqkFh + 65536, WqkFl + 65536, Lsz, 0, 32);
    packA_rm<<<dim3(64, 1), 256, 0, stream>>>(W_txt_fc, WfcFh, WfcFl, Rsz + Lsz, Lsz, 4);

    // 2) image-side precompute + generated weights, then frag-pack weights
    img_kernel<<<64, 256, 0, stream>>>(img_embed, W_reduce_img, b_reduce_img, base, iv);
    genw_gemm<<<dim3(3, 129, 2), 256, 0, stream>>>(gen_Wih, gen_bih, gen_Whh, gen_bhh,
        gen_Wbih, gen_bbih, gen_Wbhh, gen_bbhh, base, WihAllT, WhhAllT, bihAll, bhhAll);
    packwhh_kernel<<<dim3(8, 192, 2), 256, 0, stream>>>(gru_Whh_f, gru_Whh_b, WhhFh, WhhFl);
    packgenw_kernel<<<dim3(24, 2, 64), 256, 0, stream>>>(WihAllT, WhhAllT, WgenFh, WgenFl);

    // 3) gi (both dirs, MFMA) + cap_reduced + its frag pack
    gemm_mfma<<<dim3(16, 24), 256, 0, stream>>>(WihFh, WihFl, capBFh, capBFl,
        gru_bih_f, giT2_f, 10, NC);
    gemm_mfma<<<dim3(16, 24), 256, 0, stream>>>(WihFh + 491520, WihFl + 491520,
        capBFh, capBFl, gru_bih_b, giT2_b, 10, NC);
    gemm_tt<<<dim3(16, 1, 1), 256, 0, stream>>>(WrtT, WrtT, capTr,
        b_reduce_txt, b_reduce_txt, capT2, capT2, Rsz);
    packcap_kernel<<<128, 256, 0, stream>>>(capT2, capFh, capFl);

    // 4) recurrences: one fused kernel per step (coop grid.sync measured
    //    at ~12us/step on 8-XCD -> per-step launches are faster)
    for (int s = 0; s < Tsz; s++) {
        rec_kernel<<<384, 256, 0, stream>>>(WhhFh, WhhFl, WgenFh, WgenFl,
            capFh, capFl, capHFh, capHFl, genHFh, genHFl, giT2_f, giT2_b,
            hfT, hbT, gru_bhh_f, gru_bhh_b, bihAll, bhhAll, hA, hB, hmaxT, s);
    }
    hstdT_kernel<<<64, 256, 0, stream>>>(hmaxT, hstdT);

    // 5) combine + self-attention (q/k/v via MFMA GEMMs)
    txt_combine<<<dim3(32, 16), 256, 0, stream>>>(hfT, hbT, txt, txtT);
    packB_kernel<<<dim3(128, 8), 256, 0, stream>>>(txtT, txtFh, txtFl, NC, 32);
    packB_kernel<<<dim3(256, 1), 256, 0, stream>>>(hstdT, hstdFh, hstdFl, 4096, 4);
    gemm_mfma<<<dim3(16, 2), 256, 0, stream>>>(WqkFh, WqkFl, txtFh, txtFl,
        nullptr, qkbuf, 32, NC);
    gemm_mfma<<<dim3(16, 8), 256, 0, stream>>>(WvFh, WvFl, txtFh, txtFl,
        sa_bv, vbuf, 32, NC);
    qkc_kernel<<<dim3(32, 2), 256, 0, stream>>>(qkbuf, sa_bq, sa_bk, qbuf, kbuf);
    attn_kernel<<<dim3(64, 8), 256, 0, stream>>>(qbuf, kbuf, vbuf, txt,
        sa_gamma, xattn);

    // 6) pool + image-independent FC part (transposed output)
    pool_kernel<<<dim3(64, 4), 256, 0, stream>>>(xattn, lens, txt_emb);
    basefc_kernel<<<256, 256, 0, stream>>>(txt_emb, W_txt_fc, base_fcT);

    // 7) fc delta (column layout, MFMA) + sims partial/final
    gemm_mfma<<<dim3(32, 8), 256, 0, stream>>>(WfcFh, WfcFl, hstdFh, hstdFl,
        nullptr, fcT, 4, 4096);
    sims_part<<<dim3(64, 4), 256, 0, stream>>>(fcT, base_fcT, b_txt_fc, iv, accA, accB);
    sims_final<<<16, 256, 0, stream>>>(accA, accB, (float*)d_out);
}